// Round 21
// baseline (76.070 us; speedup 1.0000x reference)
//
#include <hip/hip_runtime.h>
#include <hip/hip_bf16.h>

typedef unsigned short u16;
typedef __attribute__((ext_vector_type(8))) __bf16 bf16x8;
typedef __attribute__((ext_vector_type(4))) float f32x4;

#define B_ 4
#define T_ 2048
#define C_ 1024
#define H_ 64
#define NSEG 8

__device__ __forceinline__ u16 f2bf(float f) {
    union { __hip_bfloat16 h; u16 u; } cv;
    cv.h = __float2bfloat16(f);
    return cv.u;
}

__device__ __forceinline__ float bf2f(unsigned v) {
    union { unsigned u; float f; } c; c.u = v << 16; return c.f;
}

__device__ __forceinline__ bf16x8 cvt8r(float4 f0, float4 f1) {
    union { u16 h[8]; bf16x8 v; } ua;
    ua.h[0] = f2bf(f0.x); ua.h[1] = f2bf(f0.y);
    ua.h[2] = f2bf(f0.z); ua.h[3] = f2bf(f0.w);
    ua.h[4] = f2bf(f1.x); ua.h[5] = f2bf(f1.y);
    ua.h[6] = f2bf(f1.z); ua.h[7] = f2bf(f1.w);
    return ua.v;
}

// async global -> LDS, 16B per lane; LDS dest = uniform base + lane*16
__device__ __forceinline__ void gll16(const void* g, void* l) {
    __builtin_amdgcn_global_load_lds(
        (const __attribute__((address_space(1))) void*)g,
        (__attribute__((address_space(3))) void*)l, 16, 0, 0);
}

// ---------------- Kernel 0: W fp32 -> FRAGMENT-PACKED bf16 ----------------
__global__ __launch_bounds__(256) void wpack(
    const float* __restrict__ wq, const float* __restrict__ wk,
    const float* __restrict__ wv, u16* __restrict__ wP)
{
    int u    = blockIdx.x * 256 + threadIdx.x;   // 0..24575
    int ln   = u & 63;
    int frag = u >> 6;                           // 0..383
    int ksg  = frag & 31;
    int j16  = frag >> 5;                        // 0..11
    int n    = j16 * 16 + (ln & 15);
    int kb   = ksg * 32 + (ln >> 4) * 8;
    const float* src = (n < 64) ? (wq + (size_t)n * C_)
                     : (n < 128) ? (wk + (size_t)(n - 64) * C_)
                                 : (wv + (size_t)(n - 128) * C_);
    float4 f0 = *(const float4*)(src + kb);
    float4 f1 = *(const float4*)(src + kb + 4);
    *(bf16x8*)(wP + (size_t)u * 8) = cvt8r(f0, f1);
}

// ---------------- Kernel 1: QKV projection -> FRAGMENT-PACKED outputs -----
__global__ __launch_bounds__(512) void qkv(
    const float* __restrict__ x, const u16* __restrict__ wP,
    u16* __restrict__ qP, u16* __restrict__ kP, u16* __restrict__ vP)
{
    __shared__ __align__(16) char smem[32768];

    const int tid = threadIdx.x;
    const int ln  = tid & 63;
    const int w   = tid >> 6;                    // 0..7
    const int m0  = blockIdx.x * 32;

    const int lr = ln & 15;
    const int g  = ln >> 4;
    const int ms = w >> 2;
    const int nh = w & 3;

    f32x4 acc[3] = {};

    const int xrow = w * 4 + (ln >> 4);
    const int xc   = (ln & 15) ^ (xrow & 7);

#define STAGE(BUF, KC)                                                     \
    gll16(x + (size_t)(m0 + xrow) * C_ + (KC) * 64 + xc * 4,               \
          smem + (BUF) * 8192 + w * 1024)

    STAGE(0, 0);
    __syncthreads();

    const int ra  = ms * 16 + lr;
    const int rsw = ra & 7;
    const u16* wbase = wP + (size_t)(nh * 3) * 32 * 64 * 8;

    for (int kc = 0; kc < 16; ++kc) {
        const int buf = kc & 1;
        if (kc < 15) STAGE(buf ^ 1, kc + 1);

        const char* rb = smem + buf * 8192;

        bf16x8 a[2];
        #pragma unroll
        for (int ks = 0; ks < 2; ++ks) {
            int c0 = ks * 8 + g * 2;
            float4 fa = *(const float4*)(rb + ra * 256 + ((c0       ^ rsw) << 4));
            float4 fb = *(const float4*)(rb + ra * 256 + (((c0 + 1) ^ rsw) << 4));
            a[ks] = cvt8r(fa, fb);
        }

        #pragma unroll
        for (int j = 0; j < 3; ++j) {
            #pragma unroll
            for (int ks = 0; ks < 2; ++ks) {
                size_t fragofs = ((size_t)(j * 32 + kc * 2 + ks) * 64 + ln) * 8;
                bf16x8 b = *(const bf16x8*)(wbase + fragofs);
                acc[j] = __builtin_amdgcn_mfma_f32_16x16x32_bf16(a[ks], b, acc[j], 0, 0, 0);
            }
        }

        __syncthreads();
    }
#undef STAGE

    // epilogue: acc -> LDS f32 tile [32][201] -> packed coalesced writes
    float* tile = (float*)smem;
    #pragma unroll
    for (int j = 0; j < 3; ++j)
        #pragma unroll
        for (int i = 0; i < 4; ++i)
            tile[(ms * 16 + g * 4 + i) * 201 + nh * 48 + j * 16 + lr] = acc[j][i];
    __syncthreads();

    for (int uu = tid; uu < 768; uu += 512) {
        const int ln2 = uu & 63;
        const int lr2 = ln2 & 15;
        const int g2  = ln2 >> 4;
        if (uu < 512) {
            const int isK = uu >> 8;
            const int rem = uu & 255;
            const int u   = rem >> 7;
            const int ks  = (rem >> 6) & 1;
            const float* src = tile + (u * 16 + lr2) * 201 + isK * 64 + ks * 32 + g2 * 8;
            float4 f0 = *(const float4*)src;
            float4 f1 = *(const float4*)(src + 4);
            bf16x8 val = cvt8r(f0, f1);
            u16* dst = (isK ? kP : qP)
                     + ((size_t)(((m0 >> 4) + u) * 2 + ks) * 64 + ln2) * 8;
            *(bf16x8*)dst = val;
        } else {
            const int rem = uu - 512;
            const int jf  = rem >> 6;
            union { u16 h[8]; bf16x8 v; } ua;
            #pragma unroll
            for (int e = 0; e < 8; ++e)
                ua.h[e] = f2bf(tile[(g2 * 8 + e) * 201 + 128 + jf * 16 + lr2]);
            u16* dst = vP + ((size_t)((m0 >> 5) * 4 + jf) * 64 + ln2) * 8;
            *(bf16x8*)dst = ua.v;
        }
    }
}

// ---------------- Kernel 2: causal flash attention, KV-split x8 ----------
// All fragment loads are contiguous 1KB wave loads from packed buffers.
__global__ __launch_bounds__(64) void attn_part(
    const u16* __restrict__ qP, const u16* __restrict__ kP,
    const u16* __restrict__ vP, u16* __restrict__ opart,
    float* __restrict__ ml)
{
    __shared__ u16 ps[16 * 72];

    const int lane = threadIdx.x;
    const int bid  = blockIdx.x;
    const int seg  = bid & (NSEG - 1);
    const int tix  = bid >> 3;
    const int b    = tix & 3;
    const int qt   = 127 - (tix >> 2);
    const int q0   = qt * 16;

    const int lr = lane & 15;
    const int g  = lane >> 4;
    const int lk = g * 8;

    const int nch = (qt >> 2) + 1;
    const int L   = (nch + NSEG - 1) >> 3;
    const int c0  = seg * L;
    const int c1  = min(nch, c0 + L);

    if (c0 >= c1) {
        if (lr == 0)
            #pragma unroll
            for (int i = 0; i < 4; ++i) {
                ml[(size_t)bid * 32 + (g * 4 + i) * 2]     = -1e30f;
                ml[(size_t)bid * 32 + (g * 4 + i) * 2 + 1] = 0.f;
            }
        return;
    }

    // Q fragments: packed contiguous
    bf16x8 aq[2];
    #pragma unroll
    for (int ks = 0; ks < 2; ++ks)
        aq[ks] = *(const bf16x8*)(qP + ((size_t)((b * 128 + qt) * 2 + ks) * 64 + lane) * 8);

    f32x4 oacc[4] = {};
    float mrow[4], lrow[4];
    #pragma unroll
    for (int i = 0; i < 4; ++i) { mrow[i] = -1e30f; lrow[i] = 0.f; }

    for (int jc = c0; jc < c1; ++jc) {
        const int kv0 = jc << 6;

        bf16x8 bk[8];
        #pragma unroll
        for (int jf = 0; jf < 4; ++jf)
            #pragma unroll
            for (int ks = 0; ks < 2; ++ks)
                bk[jf * 2 + ks] = *(const bf16x8*)(kP +
                    ((size_t)((b * 128 + (kv0 >> 4) + jf) * 2 + ks) * 64 + lane) * 8);

        f32x4 sacc[4] = {};
        #pragma unroll
        for (int jf = 0; jf < 4; ++jf)
            #pragma unroll
            for (int ks = 0; ks < 2; ++ks)
                sacc[jf] = __builtin_amdgcn_mfma_f32_16x16x32_bf16(aq[ks], bk[jf * 2 + ks], sacc[jf], 0, 0, 0);

        // V fragments (contiguous) issued BEFORE softmax
        bf16x8 bv[8];
        #pragma unroll
        for (int ks2 = 0; ks2 < 2; ++ks2)
            #pragma unroll
            for (int jf = 0; jf < 4; ++jf)
                bv[jf * 2 + ks2] = *(const bf16x8*)(vP +
                    ((size_t)((b * 64 + (kv0 >> 5) + ks2) * 4 + jf) * 64 + lane) * 8);

        const bool full = (kv0 + 63 <= q0);
        #pragma unroll
        for (int jf = 0; jf < 4; ++jf) {
            int col = kv0 + jf * 16 + lr;
            #pragma unroll
            for (int i = 0; i < 4; ++i) {
                int row = q0 + g * 4 + i;
                float val = sacc[jf][i] * 0.03125f;
                sacc[jf][i] = (full || col <= row) ? val : -1e30f;
            }
        }

        float pnew[4][4];
        #pragma unroll
        for (int i = 0; i < 4; ++i) {
            float mx = fmaxf(fmaxf(sacc[0][i], sacc[1][i]), fmaxf(sacc[2][i], sacc[3][i]));
            mx = fmaxf(mx, __shfl_xor(mx, 1));
            mx = fmaxf(mx, __shfl_xor(mx, 2));
            mx = fmaxf(mx, __shfl_xor(mx, 4));
            mx = fmaxf(mx, __shfl_xor(mx, 8));
            float mnew = fmaxf(mrow[i], mx);
            float corr = __expf(mrow[i] - mnew);
            float rs = 0.f;
            #pragma unroll
            for (int jf = 0; jf < 4; ++jf) {
                float p = __expf(sacc[jf][i] - mnew);
                pnew[jf][i] = p;
                rs += p;
            }
            rs += __shfl_xor(rs, 1);
            rs += __shfl_xor(rs, 2);
            rs += __shfl_xor(rs, 4);
            rs += __shfl_xor(rs, 8);
            lrow[i] = lrow[i] * corr + rs;
            mrow[i] = mnew;
            #pragma unroll
            for (int jf = 0; jf < 4; ++jf) oacc[jf][i] *= corr;
        }

        // P -> LDS (C/D -> A layout) -- single wave, ordering via lgkmcnt
        #pragma unroll
        for (int jf = 0; jf < 4; ++jf)
            #pragma unroll
            for (int i = 0; i < 4; ++i)
                ps[(g * 4 + i) * 72 + jf * 16 + lr] = f2bf(pnew[jf][i]);

        #pragma unroll
        for (int ks2 = 0; ks2 < 2; ++ks2) {
            bf16x8 ap = *(const bf16x8*)(ps + lr * 72 + ks2 * 32 + lk);
            #pragma unroll
            for (int jf = 0; jf < 4; ++jf)
                oacc[jf] = __builtin_amdgcn_mfma_f32_16x16x32_bf16(ap, bv[jf * 2 + ks2], oacc[jf], 0, 0, 0);
        }
    }

    #pragma unroll
    for (int jf = 0; jf < 4; ++jf)
        #pragma unroll
        for (int i = 0; i < 4; ++i)
            opart[(size_t)bid * 1024 + (g * 4 + i) * 64 + jf * 16 + lr] = f2bf(oacc[jf][i]);
    if (lr == 0)
        #pragma unroll
        for (int i = 0; i < 4; ++i) {
            ml[(size_t)bid * 32 + (g * 4 + i) * 2]     = mrow[i];
            ml[(size_t)bid * 32 + (g * 4 + i) * 2 + 1] = lrow[i];
        }
}

// ---------------- Kernel 3: merge segments (bf16 partials) ----------------
__global__ __launch_bounds__(256) void attn_reduce(
    const u16* __restrict__ opart, const float* __restrict__ ml,
    float* __restrict__ out)
{
    const int t   = blockIdx.x;
    const int row = threadIdx.x >> 4;
    const int p   = threadIdx.x & 15;
    const int b   = t & 3;
    const int qt  = 127 - (t >> 2);

    float m[NSEG], l[NSEG];
    #pragma unroll
    for (int s = 0; s < NSEG; ++s) {
        m[s] = ml[(size_t)(t * NSEG + s) * 32 + row * 2];
        l[s] = ml[(size_t)(t * NSEG + s) * 32 + row * 2 + 1];
    }
    float M = m[0];
    #pragma unroll
    for (int s = 1; s < NSEG; ++s) M = fmaxf(M, m[s]);

    float a0 = 0.f, a1 = 0.f, a2 = 0.f, a3 = 0.f, Lsum = 0.f;
    #pragma unroll
    for (int s = 0; s < NSEG; ++s) {
        float wgt = __expf(m[s] - M);
        Lsum += l[s] * wgt;
        uint2 o = *(const uint2*)(opart + (size_t)(t * NSEG + s) * 1024 + row * 64 + p * 4);
        a0 += wgt * bf2f(o.x & 0xffffu);
        a1 += wgt * bf2f(o.x >> 16);
        a2 += wgt * bf2f(o.y & 0xffffu);
        a3 += wgt * bf2f(o.y >> 16);
    }
    float inv = 1.f / Lsum;
    float4 r; r.x = a0 * inv; r.y = a1 * inv; r.z = a2 * inv; r.w = a3 * inv;
    *(float4*)(out + ((size_t)b * T_ + qt * 16 + row) * H_ + p * 4) = r;
}

extern "C" void kernel_launch(void* const* d_in, const int* in_sizes, int n_in,
                              void* d_out, int out_size, void* d_ws, size_t ws_size,
                              hipStream_t stream) {
    const float* x  = (const float*)d_in[0];
    const float* wq = (const float*)d_in[1];
    const float* wk = (const float*)d_in[2];
    const float* wv = (const float*)d_in[3];

    u16* qPws = (u16*)d_ws;                          // 1 MB
    u16* kPws = qPws + (size_t)B_ * T_ * H_;         // 1 MB
    u16* vPws = kPws + (size_t)B_ * T_ * H_;         // 1 MB
    u16* wPws = vPws + (size_t)B_ * T_ * H_;         // 384 KB
    u16* opart = wPws + (size_t)192 * C_;            // 8.4 MB
    float* mlbuf = (float*)(opart + (size_t)4096 * 1024);  // 512 KB

    wpack<<<96, 256, 0, stream>>>(wq, wk, wv, wPws);
    // MEASUREMENT: qkv launched 3x (idempotent). qkv_time = (dur_us - 41.1)/2.
    qkv<<<256, 512, 0, stream>>>(x, wPws, qPws, kPws, vPws);
    qkv<<<256, 512, 0, stream>>>(x, wPws, qPws, kPws, vPws);
    qkv<<<256, 512, 0, stream>>>(x, wPws, qPws, kPws, vPws);
    attn_part<<<4096, 64, 0, stream>>>(qPws, kPws, vPws, opart, mlbuf);
    attn_reduce<<<512, 256, 0, stream>>>(opart, mlbuf, (float*)d_out);
}

// Round 22
// 52.568 us; speedup vs baseline: 1.4471x; 1.4471x over previous
//
#include <hip/hip_runtime.h>
#include <hip/hip_bf16.h>

typedef unsigned short u16;
typedef __attribute__((ext_vector_type(8))) __bf16 bf16x8;
typedef __attribute__((ext_vector_type(4))) float f32x4;

#define B_ 4
#define T_ 2048
#define C_ 1024
#define H_ 64
#define NSEG 8

__device__ __forceinline__ u16 f2bf(float f) {
    union { __hip_bfloat16 h; u16 u; } cv;
    cv.h = __float2bfloat16(f);
    return cv.u;
}

__device__ __forceinline__ float bf2f(unsigned v) {
    union { unsigned u; float f; } c; c.u = v << 16; return c.f;
}

__device__ __forceinline__ bf16x8 cvt8r(float4 f0, float4 f1) {
    union { u16 h[8]; bf16x8 v; } ua;
    ua.h[0] = f2bf(f0.x); ua.h[1] = f2bf(f0.y);
    ua.h[2] = f2bf(f0.z); ua.h[3] = f2bf(f0.w);
    ua.h[4] = f2bf(f1.x); ua.h[5] = f2bf(f1.y);
    ua.h[6] = f2bf(f1.z); ua.h[7] = f2bf(f1.w);
    return ua.v;
}

// ---------------- Kernel 0: W fp32 -> FRAGMENT-PACKED bf16 ----------------
__global__ __launch_bounds__(256) void wpack(
    const float* __restrict__ wq, const float* __restrict__ wk,
    const float* __restrict__ wv, u16* __restrict__ wP)
{
    int u    = blockIdx.x * 256 + threadIdx.x;   // 0..24575
    int ln   = u & 63;
    int frag = u >> 6;                           // 0..383
    int ksg  = frag & 31;
    int j16  = frag >> 5;                        // 0..11
    int n    = j16 * 16 + (ln & 15);
    int kb   = ksg * 32 + (ln >> 4) * 8;
    const float* src = (n < 64) ? (wq + (size_t)n * C_)
                     : (n < 128) ? (wk + (size_t)(n - 64) * C_)
                                 : (wv + (size_t)(n - 128) * C_);
    float4 f0 = *(const float4*)(src + kb);
    float4 f1 = *(const float4*)(src + kb + 4);
    *(bf16x8*)(wP + (size_t)u * 8) = cvt8r(f0, f1);
}

// ---------------- Kernel 1: QKV projection, BARRIER-FREE main loop --------
// 256 blocks x 512 thr (8 independent waves: ms=w>>2, nh=w&3; 16x48 output).
// A-fragments loaded directly from fp32 x (16 fully-consumed lines per load
// pair), B-fragments contiguous from packed wP (L2-hot). No LDS / syncs in
// the K-loop -> compiler pipelines chunks; no vmcnt(0) barrier drains.
__global__ __launch_bounds__(512) void qkv(
    const float* __restrict__ x, const u16* __restrict__ wP,
    u16* __restrict__ qP, u16* __restrict__ kP, u16* __restrict__ vP)
{
    __shared__ float tile[32 * 201];             // epilogue only (25.7 KB)

    const int tid = threadIdx.x;
    const int ln  = tid & 63;
    const int w   = tid >> 6;                    // 0..7
    const int m0  = blockIdx.x * 32;

    const int lr = ln & 15;
    const int g  = ln >> 4;
    const int ms = w >> 2;                       // 0..1 (16-row half)
    const int nh = w & 3;                        // 0..3 (48-col quarter)

    f32x4 acc[3] = {};

    const float* xbase = x + (size_t)(m0 + ms * 16 + lr) * C_ + g * 8;
    const u16*   wbase = wP + (size_t)(nh * 3) * 32 * 64 * 8;

    #pragma unroll 4
    for (int kc = 0; kc < 16; ++kc) {
        // A fragments: direct fp32 loads (paired 16B hits on same 16 lines)
        bf16x8 a[2];
        #pragma unroll
        for (int ks = 0; ks < 2; ++ks) {
            const float* p = xbase + kc * 64 + ks * 32;
            float4 f0 = *(const float4*)(p);
            float4 f1 = *(const float4*)(p + 4);
            a[ks] = cvt8r(f0, f1);
        }

        // B fragments: contiguous 1KB wave loads from packed W (L2)
        #pragma unroll
        for (int j = 0; j < 3; ++j) {
            #pragma unroll
            for (int ks = 0; ks < 2; ++ks) {
                size_t fragofs = ((size_t)(j * 32 + kc * 2 + ks) * 64 + ln) * 8;
                bf16x8 b = *(const bf16x8*)(wbase + fragofs);
                acc[j] = __builtin_amdgcn_mfma_f32_16x16x32_bf16(a[ks], b, acc[j], 0, 0, 0);
            }
        }
    }

    // epilogue: acc -> LDS f32 tile [32][201] -> packed coalesced writes
    #pragma unroll
    for (int j = 0; j < 3; ++j)
        #pragma unroll
        for (int i = 0; i < 4; ++i)
            tile[(ms * 16 + g * 4 + i) * 201 + nh * 48 + j * 16 + lr] = acc[j][i];
    __syncthreads();

    for (int uu = tid; uu < 768; uu += 512) {
        const int ln2 = uu & 63;
        const int lr2 = ln2 & 15;
        const int g2  = ln2 >> 4;
        if (uu < 512) {
            const int isK = uu >> 8;
            const int rem = uu & 255;
            const int u   = rem >> 7;
            const int ks  = (rem >> 6) & 1;
            const float* src = tile + (u * 16 + lr2) * 201 + isK * 64 + ks * 32 + g2 * 8;
            float4 f0 = *(const float4*)src;
            float4 f1 = *(const float4*)(src + 4);
            bf16x8 val = cvt8r(f0, f1);
            u16* dst = (isK ? kP : qP)
                     + ((size_t)(((m0 >> 4) + u) * 2 + ks) * 64 + ln2) * 8;
            *(bf16x8*)dst = val;
        } else {
            const int rem = uu - 512;
            const int jf  = rem >> 6;
            union { u16 h[8]; bf16x8 v; } ua;
            #pragma unroll
            for (int e = 0; e < 8; ++e)
                ua.h[e] = f2bf(tile[(g2 * 8 + e) * 201 + 128 + jf * 16 + lr2]);
            u16* dst = vP + ((size_t)((m0 >> 5) * 4 + jf) * 64 + ln2) * 8;
            *(bf16x8*)dst = ua.v;
        }
    }
}

// ---------------- Kernel 2: causal flash attention, KV-split x8 ----------
// All fragment loads are contiguous 1KB wave loads from packed buffers.
__global__ __launch_bounds__(64) void attn_part(
    const u16* __restrict__ qP, const u16* __restrict__ kP,
    const u16* __restrict__ vP, u16* __restrict__ opart,
    float* __restrict__ ml)
{
    __shared__ u16 ps[16 * 72];

    const int lane = threadIdx.x;
    const int bid  = blockIdx.x;
    const int seg  = bid & (NSEG - 1);
    const int tix  = bid >> 3;
    const int b    = tix & 3;
    const int qt   = 127 - (tix >> 2);
    const int q0   = qt * 16;

    const int lr = lane & 15;
    const int g  = lane >> 4;
    const int lk = g * 8;

    const int nch = (qt >> 2) + 1;
    const int L   = (nch + NSEG - 1) >> 3;
    const int c0  = seg * L;
    const int c1  = min(nch, c0 + L);

    if (c0 >= c1) {
        if (lr == 0)
            #pragma unroll
            for (int i = 0; i < 4; ++i) {
                ml[(size_t)bid * 32 + (g * 4 + i) * 2]     = -1e30f;
                ml[(size_t)bid * 32 + (g * 4 + i) * 2 + 1] = 0.f;
            }
        return;
    }

    // Q fragments: packed contiguous
    bf16x8 aq[2];
    #pragma unroll
    for (int ks = 0; ks < 2; ++ks)
        aq[ks] = *(const bf16x8*)(qP + ((size_t)((b * 128 + qt) * 2 + ks) * 64 + lane) * 8);

    f32x4 oacc[4] = {};
    float mrow[4], lrow[4];
    #pragma unroll
    for (int i = 0; i < 4; ++i) { mrow[i] = -1e30f; lrow[i] = 0.f; }

    for (int jc = c0; jc < c1; ++jc) {
        const int kv0 = jc << 6;

        bf16x8 bk[8];
        #pragma unroll
        for (int jf = 0; jf < 4; ++jf)
            #pragma unroll
            for (int ks = 0; ks < 2; ++ks)
                bk[jf * 2 + ks] = *(const bf16x8*)(kP +
                    ((size_t)((b * 128 + (kv0 >> 4) + jf) * 2 + ks) * 64 + lane) * 8);

        f32x4 sacc[4] = {};
        #pragma unroll
        for (int jf = 0; jf < 4; ++jf)
            #pragma unroll
            for (int ks = 0; ks < 2; ++ks)
                sacc[jf] = __builtin_amdgcn_mfma_f32_16x16x32_bf16(aq[ks], bk[jf * 2 + ks], sacc[jf], 0, 0, 0);

        // V fragments (contiguous) issued BEFORE softmax
        bf16x8 bv[8];
        #pragma unroll
        for (int ks2 = 0; ks2 < 2; ++ks2)
            #pragma unroll
            for (int jf = 0; jf < 4; ++jf)
                bv[jf * 2 + ks2] = *(const bf16x8*)(vP +
                    ((size_t)((b * 64 + (kv0 >> 5) + ks2) * 4 + jf) * 64 + lane) * 8);

        const bool full = (kv0 + 63 <= q0);
        #pragma unroll
        for (int jf = 0; jf < 4; ++jf) {
            int col = kv0 + jf * 16 + lr;
            #pragma unroll
            for (int i = 0; i < 4; ++i) {
                int row = q0 + g * 4 + i;
                float val = sacc[jf][i] * 0.03125f;
                sacc[jf][i] = (full || col <= row) ? val : -1e30f;
            }
        }

        float pnew[4][4];
        #pragma unroll
        for (int i = 0; i < 4; ++i) {
            float mx = fmaxf(fmaxf(sacc[0][i], sacc[1][i]), fmaxf(sacc[2][i], sacc[3][i]));
            mx = fmaxf(mx, __shfl_xor(mx, 1));
            mx = fmaxf(mx, __shfl_xor(mx, 2));
            mx = fmaxf(mx, __shfl_xor(mx, 4));
            mx = fmaxf(mx, __shfl_xor(mx, 8));
            float mnew = fmaxf(mrow[i], mx);
            float corr = __expf(mrow[i] - mnew);
            float rs = 0.f;
            #pragma unroll
            for (int jf = 0; jf < 4; ++jf) {
                float p = __expf(sacc[jf][i] - mnew);
                pnew[jf][i] = p;
                rs += p;
            }
            rs += __shfl_xor(rs, 1);
            rs += __shfl_xor(rs, 2);
            rs += __shfl_xor(rs, 4);
            rs += __shfl_xor(rs, 8);
            lrow[i] = lrow[i] * corr + rs;
            mrow[i] = mnew;
            #pragma unroll
            for (int jf = 0; jf < 4; ++jf) oacc[jf][i] *= corr;
        }

        // P -> LDS (C/D -> A layout) -- single wave, ordering via lgkmcnt
        #pragma unroll
        for (int jf = 0; jf < 4; ++jf)
            #pragma unroll
            for (int i = 0; i < 4; ++i)
                ps[(g * 4 + i) * 72 + jf * 16 + lr] = f2bf(pnew[jf][i]);

        #pragma unroll
        for (int ks2 = 0; ks2 < 2; ++ks2) {
            bf16x8 ap = *(const bf16x8*)(ps + lr * 72 + ks2 * 32 + lk);
            #pragma unroll
            for (int jf = 0; jf < 4; ++jf)
                oacc[jf] = __builtin_amdgcn_mfma_f32_16x16x32_bf16(ap, bv[jf * 2 + ks2], oacc[jf], 0, 0, 0);
        }
    }

    #pragma unroll
    for (int jf = 0; jf < 4; ++jf)
        #pragma unroll
        for (int i = 0; i < 4; ++i)
            opart[(size_t)bid * 1024 + (g * 4 + i) * 64 + jf * 16 + lr] = f2bf(oacc[jf][i]);
    if (lr == 0)
        #pragma unroll
        for (int i = 0; i < 4; ++i) {
            ml[(size_t)bid * 32 + (g * 4 + i) * 2]     = mrow[i];
            ml[(size_t)bid * 32 + (g * 4 + i) * 2 + 1] = lrow[i];
        }
}

// ---------------- Kernel 3: merge segments (bf16 partials) ----------------
__global__ __launch_bounds__(256) void attn_reduce(
    const u16* __restrict__ opart, const float* __restrict__ ml,
    float* __restrict__ out)
{
    const int t   = blockIdx.x;
    const int row = threadIdx.x >> 4;
    const int p   = threadIdx.x & 15;
    const int b   = t & 3;
    const int qt  = 127 - (t >> 2);

    float m[NSEG], l[NSEG];
    #pragma unroll
    for (int s = 0; s < NSEG; ++s) {
        m[s] = ml[(size_t)(t * NSEG + s) * 32 + row * 2];
        l[s] = ml[(size_t)(t * NSEG + s) * 32 + row * 2 + 1];
    }
    float M = m[0];
    #pragma unroll
    for (int s = 1; s < NSEG; ++s) M = fmaxf(M, m[s]);

    float a0 = 0.f, a1 = 0.f, a2 = 0.f, a3 = 0.f, Lsum = 0.f;
    #pragma unroll
    for (int s = 0; s < NSEG; ++s) {
        float wgt = __expf(m[s] - M);
        Lsum += l[s] * wgt;
        uint2 o = *(const uint2*)(opart + (size_t)(t * NSEG + s) * 1024 + row * 64 + p * 4);
        a0 += wgt * bf2f(o.x & 0xffffu);
        a1 += wgt * bf2f(o.x >> 16);
        a2 += wgt * bf2f(o.y & 0xffffu);
        a3 += wgt * bf2f(o.y >> 16);
    }
    float inv = 1.f / Lsum;
    float4 r; r.x = a0 * inv; r.y = a1 * inv; r.z = a2 * inv; r.w = a3 * inv;
    *(float4*)(out + ((size_t)b * T_ + qt * 16 + row) * H_ + p * 4) = r;
}

extern "C" void kernel_launch(void* const* d_in, const int* in_sizes, int n_in,
                              void* d_out, int out_size, void* d_ws, size_t ws_size,
                              hipStream_t stream) {
    const float* x  = (const float*)d_in[0];
    const float* wq = (const float*)d_in[1];
    const float* wk = (const float*)d_in[2];
    const float* wv = (const float*)d_in[3];

    u16* qPws = (u16*)d_ws;                          // 1 MB
    u16* kPws = qPws + (size_t)B_ * T_ * H_;         // 1 MB
    u16* vPws = kPws + (size_t)B_ * T_ * H_;         // 1 MB
    u16* wPws = vPws + (size_t)B_ * T_ * H_;         // 384 KB
    u16* opart = wPws + (size_t)192 * C_;            // 8.4 MB
    float* mlbuf = (float*)(opart + (size_t)4096 * 1024);  // 512 KB

    wpack<<<96, 256, 0, stream>>>(wq, wk, wv, wPws);
    qkv<<<256, 512, 0, stream>>>(x, wPws, qPws, kPws, vPws);
    attn_part<<<4096, 64, 0, stream>>>(qPws, kPws, vPws, opart, mlbuf);
    attn_reduce<<<512, 256, 0, stream>>>(opart, mlbuf, (float*)d_out);
}

// Round 23
// 48.410 us; speedup vs baseline: 1.5714x; 1.0859x over previous
//
#include <hip/hip_runtime.h>
#include <hip/hip_bf16.h>

typedef unsigned short u16;
typedef __attribute__((ext_vector_type(8))) __bf16 bf16x8;
typedef __attribute__((ext_vector_type(4))) float f32x4;

#define B_ 4
#define T_ 2048
#define C_ 1024
#define H_ 64
#define NSEG 8

__device__ __forceinline__ u16 f2bf(float f) {
    union { __hip_bfloat16 h; u16 u; } cv;
    cv.h = __float2bfloat16(f);
    return cv.u;
}

__device__ __forceinline__ float bf2f(unsigned v) {
    union { unsigned u; float f; } c; c.u = v << 16; return c.f;
}

__device__ __forceinline__ bf16x8 cvt8r(float4 f0, float4 f1) {
    union { u16 h[8]; bf16x8 v; } ua;
    ua.h[0] = f2bf(f0.x); ua.h[1] = f2bf(f0.y);
    ua.h[2] = f2bf(f0.z); ua.h[3] = f2bf(f0.w);
    ua.h[4] = f2bf(f1.x); ua.h[5] = f2bf(f1.y);
    ua.h[6] = f2bf(f1.z); ua.h[7] = f2bf(f1.w);
    return ua.v;
}

// ---------------- Kernel 0: pack x AND W -> fragment-major bf16 -----------
// blocks 0..4095: x -> xP. Reads fully coalesced (32B/thread); writes are
// scattered 16B units (fire-and-forget).
//   xP unit = m16*32 + ksg (m16 = row>>4, ksg = k>>5);
//   lane = (row&15) + ((k>>3)&3)*16; elem = k&7.
// blocks 4096..4191: W -> wP (as before).
__global__ __launch_bounds__(256) void pack(
    const float* __restrict__ x,
    const float* __restrict__ wq, const float* __restrict__ wk,
    const float* __restrict__ wv,
    u16* __restrict__ xP, u16* __restrict__ wP)
{
    const int bid = blockIdx.x;
    if (bid < 4096) {
        size_t t = (size_t)bid * 256 + threadIdx.x;   // 0..1048575
        int m  = (int)(t >> 7);                        // row 0..8191
        int k0 = (int)(t & 127) * 8;                   // 0..1016
        float4 f0 = *(const float4*)(x + (size_t)m * C_ + k0);
        float4 f1 = *(const float4*)(x + (size_t)m * C_ + k0 + 4);
        bf16x8 v = cvt8r(f0, f1);
        int m16 = m >> 4, mr = m & 15;
        int ksg = k0 >> 5, kgrp = (k0 >> 3) & 3;
        *(bf16x8*)(xP + ((size_t)(m16 * 32 + ksg) * 64 + mr + kgrp * 16) * 8) = v;
    } else {
        int u    = (bid - 4096) * 256 + threadIdx.x;   // 0..24575
        int ln   = u & 63;
        int frag = u >> 6;
        int ksg  = frag & 31;
        int j16  = frag >> 5;                          // 0..11
        int n    = j16 * 16 + (ln & 15);
        int kb   = ksg * 32 + (ln >> 4) * 8;
        const float* src = (n < 64) ? (wq + (size_t)n * C_)
                         : (n < 128) ? (wk + (size_t)(n - 64) * C_)
                                     : (wv + (size_t)(n - 128) * C_);
        float4 f0 = *(const float4*)(src + kb);
        float4 f1 = *(const float4*)(src + kb + 4);
        *(bf16x8*)(wP + (size_t)u * 8) = cvt8r(f0, f1);
    }
}

// ---------------- Kernel 1: QKV projection, gather-free & barrier-free ----
// 256 blocks x 512 thr (8 independent waves: ms=w>>2, nh=w&3; 16x48 output).
// A-frags: contiguous 1KB wave loads from packed xP; B-frags: contiguous
// from packed wP. No LDS / syncs in the K-loop -> full compiler pipelining.
__global__ __launch_bounds__(512) void qkv(
    const u16* __restrict__ xP, const u16* __restrict__ wP,
    u16* __restrict__ qP, u16* __restrict__ kP, u16* __restrict__ vP)
{
    __shared__ float tile[32 * 201];             // epilogue only (25.7 KB)

    const int tid = threadIdx.x;
    const int ln  = tid & 63;
    const int w   = tid >> 6;                    // 0..7
    const int m0  = blockIdx.x * 32;

    const int lr = ln & 15;
    const int g  = ln >> 4;
    const int ms = w >> 2;                       // 0..1 (16-row half)
    const int nh = w & 3;                        // 0..3 (48-col quarter)

    f32x4 acc[3] = {};

    const u16* xbase = xP + (size_t)((m0 >> 4) + ms) * 32 * 64 * 8 + (size_t)ln * 8;
    const u16* wbase = wP + (size_t)(nh * 3) * 32 * 64 * 8;

    #pragma unroll 4
    for (int kc = 0; kc < 16; ++kc) {
        bf16x8 a[2];
        #pragma unroll
        for (int ks = 0; ks < 2; ++ks)
            a[ks] = *(const bf16x8*)(xbase + (size_t)(kc * 2 + ks) * 64 * 8);

        #pragma unroll
        for (int j = 0; j < 3; ++j) {
            #pragma unroll
            for (int ks = 0; ks < 2; ++ks) {
                size_t fragofs = ((size_t)(j * 32 + kc * 2 + ks) * 64 + ln) * 8;
                bf16x8 b = *(const bf16x8*)(wbase + fragofs);
                acc[j] = __builtin_amdgcn_mfma_f32_16x16x32_bf16(a[ks], b, acc[j], 0, 0, 0);
            }
        }
    }

    // epilogue: acc -> LDS f32 tile [32][201] -> packed coalesced writes
    #pragma unroll
    for (int j = 0; j < 3; ++j)
        #pragma unroll
        for (int i = 0; i < 4; ++i)
            tile[(ms * 16 + g * 4 + i) * 201 + nh * 48 + j * 16 + lr] = acc[j][i];
    __syncthreads();

    for (int uu = tid; uu < 768; uu += 512) {
        const int ln2 = uu & 63;
        const int lr2 = ln2 & 15;
        const int g2  = ln2 >> 4;
        if (uu < 512) {
            const int isK = uu >> 8;
            const int rem = uu & 255;
            const int u   = rem >> 7;
            const int ks  = (rem >> 6) & 1;
            const float* src = tile + (u * 16 + lr2) * 201 + isK * 64 + ks * 32 + g2 * 8;
            float4 f0 = *(const float4*)src;
            float4 f1 = *(const float4*)(src + 4);
            bf16x8 val = cvt8r(f0, f1);
            u16* dst = (isK ? kP : qP)
                     + ((size_t)(((m0 >> 4) + u) * 2 + ks) * 64 + ln2) * 8;
            *(bf16x8*)dst = val;
        } else {
            const int rem = uu - 512;
            const int jf  = rem >> 6;
            union { u16 h[8]; bf16x8 v; } ua;
            #pragma unroll
            for (int e = 0; e < 8; ++e)
                ua.h[e] = f2bf(tile[(g2 * 8 + e) * 201 + 128 + jf * 16 + lr2]);
            u16* dst = vP + ((size_t)((m0 >> 5) * 4 + jf) * 64 + ln2) * 8;
            *(bf16x8*)dst = ua.v;
        }
    }
}

// ---------------- Kernel 2: causal flash attention, KV-split x8 ----------
__global__ __launch_bounds__(64) void attn_part(
    const u16* __restrict__ qP, const u16* __restrict__ kP,
    const u16* __restrict__ vP, u16* __restrict__ opart,
    float* __restrict__ ml)
{
    __shared__ u16 ps[16 * 72];

    const int lane = threadIdx.x;
    const int bid  = blockIdx.x;
    const int seg  = bid & (NSEG - 1);
    const int tix  = bid >> 3;
    const int b    = tix & 3;
    const int qt   = 127 - (tix >> 2);
    const int q0   = qt * 16;

    const int lr = lane & 15;
    const int g  = lane >> 4;
    const int lk = g * 8;

    const int nch = (qt >> 2) + 1;
    const int L   = (nch + NSEG - 1) >> 3;
    const int c0  = seg * L;
    const int c1  = min(nch, c0 + L);

    if (c0 >= c1) {
        if (lr == 0)
            #pragma unroll
            for (int i = 0; i < 4; ++i) {
                ml[(size_t)bid * 32 + (g * 4 + i) * 2]     = -1e30f;
                ml[(size_t)bid * 32 + (g * 4 + i) * 2 + 1] = 0.f;
            }
        return;
    }

    bf16x8 aq[2];
    #pragma unroll
    for (int ks = 0; ks < 2; ++ks)
        aq[ks] = *(const bf16x8*)(qP + ((size_t)((b * 128 + qt) * 2 + ks) * 64 + lane) * 8);

    f32x4 oacc[4] = {};
    float mrow[4], lrow[4];
    #pragma unroll
    for (int i = 0; i < 4; ++i) { mrow[i] = -1e30f; lrow[i] = 0.f; }

    for (int jc = c0; jc < c1; ++jc) {
        const int kv0 = jc << 6;

        bf16x8 bk[8];
        #pragma unroll
        for (int jf = 0; jf < 4; ++jf)
            #pragma unroll
            for (int ks = 0; ks < 2; ++ks)
                bk[jf * 2 + ks] = *(const bf16x8*)(kP +
                    ((size_t)((b * 128 + (kv0 >> 4) + jf) * 2 + ks) * 64 + lane) * 8);

        f32x4 sacc[4] = {};
        #pragma unroll
        for (int jf = 0; jf < 4; ++jf)
            #pragma unroll
            for (int ks = 0; ks < 2; ++ks)
                sacc[jf] = __builtin_amdgcn_mfma_f32_16x16x32_bf16(aq[ks], bk[jf * 2 + ks], sacc[jf], 0, 0, 0);

        bf16x8 bv[8];
        #pragma unroll
        for (int ks2 = 0; ks2 < 2; ++ks2)
            #pragma unroll
            for (int jf = 0; jf < 4; ++jf)
                bv[jf * 2 + ks2] = *(const bf16x8*)(vP +
                    ((size_t)((b * 64 + (kv0 >> 5) + ks2) * 4 + jf) * 64 + lane) * 8);

        const bool full = (kv0 + 63 <= q0);
        #pragma unroll
        for (int jf = 0; jf < 4; ++jf) {
            int col = kv0 + jf * 16 + lr;
            #pragma unroll
            for (int i = 0; i < 4; ++i) {
                int row = q0 + g * 4 + i;
                float val = sacc[jf][i] * 0.03125f;
                sacc[jf][i] = (full || col <= row) ? val : -1e30f;
            }
        }

        float pnew[4][4];
        #pragma unroll
        for (int i = 0; i < 4; ++i) {
            float mx = fmaxf(fmaxf(sacc[0][i], sacc[1][i]), fmaxf(sacc[2][i], sacc[3][i]));
            mx = fmaxf(mx, __shfl_xor(mx, 1));
            mx = fmaxf(mx, __shfl_xor(mx, 2));
            mx = fmaxf(mx, __shfl_xor(mx, 4));
            mx = fmaxf(mx, __shfl_xor(mx, 8));
            float mnew = fmaxf(mrow[i], mx);
            float corr = __expf(mrow[i] - mnew);
            float rs = 0.f;
            #pragma unroll
            for (int jf = 0; jf < 4; ++jf) {
                float p = __expf(sacc[jf][i] - mnew);
                pnew[jf][i] = p;
                rs += p;
            }
            rs += __shfl_xor(rs, 1);
            rs += __shfl_xor(rs, 2);
            rs += __shfl_xor(rs, 4);
            rs += __shfl_xor(rs, 8);
            lrow[i] = lrow[i] * corr + rs;
            mrow[i] = mnew;
            #pragma unroll
            for (int jf = 0; jf < 4; ++jf) oacc[jf][i] *= corr;
        }

        #pragma unroll
        for (int jf = 0; jf < 4; ++jf)
            #pragma unroll
            for (int i = 0; i < 4; ++i)
                ps[(g * 4 + i) * 72 + jf * 16 + lr] = f2bf(pnew[jf][i]);

        #pragma unroll
        for (int ks2 = 0; ks2 < 2; ++ks2) {
            bf16x8 ap = *(const bf16x8*)(ps + lr * 72 + ks2 * 32 + lk);
            #pragma unroll
            for (int jf = 0; jf < 4; ++jf)
                oacc[jf] = __builtin_amdgcn_mfma_f32_16x16x32_bf16(ap, bv[jf * 2 + ks2], oacc[jf], 0, 0, 0);
        }
    }

    #pragma unroll
    for (int jf = 0; jf < 4; ++jf)
        #pragma unroll
        for (int i = 0; i < 4; ++i)
            opart[(size_t)bid * 1024 + (g * 4 + i) * 64 + jf * 16 + lr] = f2bf(oacc[jf][i]);
    if (lr == 0)
        #pragma unroll
        for (int i = 0; i < 4; ++i) {
            ml[(size_t)bid * 32 + (g * 4 + i) * 2]     = mrow[i];
            ml[(size_t)bid * 32 + (g * 4 + i) * 2 + 1] = lrow[i];
        }
}

// ---------------- Kernel 3: merge segments (bf16 partials) ----------------
__global__ __launch_bounds__(256) void attn_reduce(
    const u16* __restrict__ opart, const float* __restrict__ ml,
    float* __restrict__ out)
{
    const int t   = blockIdx.x;
    const int row = threadIdx.x >> 4;
    const int p   = threadIdx.x & 15;
    const int b   = t & 3;
    const int qt  = 127 - (t >> 2);

    float m[NSEG], l[NSEG];
    #pragma unroll
    for (int s = 0; s < NSEG; ++s) {
        m[s] = ml[(size_t)(t * NSEG + s) * 32 + row * 2];
        l[s] = ml[(size_t)(t * NSEG + s) * 32 + row * 2 + 1];
    }
    float M = m[0];
    #pragma unroll
    for (int s = 1; s < NSEG; ++s) M = fmaxf(M, m[s]);

    float a0 = 0.f, a1 = 0.f, a2 = 0.f, a3 = 0.f, Lsum = 0.f;
    #pragma unroll
    for (int s = 0; s < NSEG; ++s) {
        float wgt = __expf(m[s] - M);
        Lsum += l[s] * wgt;
        uint2 o = *(const uint2*)(opart + (size_t)(t * NSEG + s) * 1024 + row * 64 + p * 4);
        a0 += wgt * bf2f(o.x & 0xffffu);
        a1 += wgt * bf2f(o.x >> 16);
        a2 += wgt * bf2f(o.y & 0xffffu);
        a3 += wgt * bf2f(o.y >> 16);
    }
    float inv = 1.f / Lsum;
    float4 r; r.x = a0 * inv; r.y = a1 * inv; r.z = a2 * inv; r.w = a3 * inv;
    *(float4*)(out + ((size_t)b * T_ + qt * 16 + row) * H_ + p * 4) = r;
}

extern "C" void kernel_launch(void* const* d_in, const int* in_sizes, int n_in,
                              void* d_out, int out_size, void* d_ws, size_t ws_size,
                              hipStream_t stream) {
    const float* x  = (const float*)d_in[0];
    const float* wq = (const float*)d_in[1];
    const float* wk = (const float*)d_in[2];
    const float* wv = (const float*)d_in[3];

    u16* qPws = (u16*)d_ws;                          // 1 MB
    u16* kPws = qPws + (size_t)B_ * T_ * H_;         // 1 MB
    u16* vPws = kPws + (size_t)B_ * T_ * H_;         // 1 MB
    u16* wPws = vPws + (size_t)B_ * T_ * H_;         // 384 KB
    u16* xPws = wPws + (size_t)192 * C_;             // 16.8 MB
    u16* opart = xPws + (size_t)B_ * T_ * C_;        // 8.4 MB
    float* mlbuf = (float*)(opart + (size_t)4096 * 1024);  // 512 KB

    pack<<<4192, 256, 0, stream>>>(x, wq, wk, wv, xPws, wPws);
    qkv<<<256, 512, 0, stream>>>(xPws, wPws, qPws, kPws, vPws);
    attn_part<<<4096, 64, 0, stream>>>(qPws, kPws, vPws, opart, mlbuf);
    attn_reduce<<<512, 256, 0, stream>>>(opart, mlbuf, (float*)d_out);
}

// Round 24
// 39.764 us; speedup vs baseline: 1.9130x; 1.2174x over previous
//
#include <hip/hip_runtime.h>
#include <hip/hip_bf16.h>

typedef unsigned short u16;
typedef __attribute__((ext_vector_type(8))) __bf16 bf16x8;
typedef __attribute__((ext_vector_type(4))) float f32x4;

#define B_ 4
#define T_ 2048
#define C_ 1024
#define H_ 64
#define NSEG 8

__device__ __forceinline__ u16 f2bf(float f) {
    union { __hip_bfloat16 h; u16 u; } cv;
    cv.h = __float2bfloat16(f);
    return cv.u;
}

__device__ __forceinline__ bf16x8 cvt8r(float4 f0, float4 f1) {
    union { u16 h[8]; bf16x8 v; } ua;
    ua.h[0] = f2bf(f0.x); ua.h[1] = f2bf(f0.y);
    ua.h[2] = f2bf(f0.z); ua.h[3] = f2bf(f0.w);
    ua.h[4] = f2bf(f1.x); ua.h[5] = f2bf(f1.y);
    ua.h[6] = f2bf(f1.z); ua.h[7] = f2bf(f1.w);
    return ua.v;
}

// async global -> LDS, 16B per lane; LDS dest = uniform base + lane*16
__device__ __forceinline__ void gll16(const void* g, void* l) {
    __builtin_amdgcn_global_load_lds(
        (const __attribute__((address_space(1))) void*)g,
        (__attribute__((address_space(3))) void*)l, 16, 0, 0);
}

// ---------------- Kernel 0: W fp32 -> FRAGMENT-PACKED bf16 ----------------
__global__ __launch_bounds__(256) void wpack(
    const float* __restrict__ wq, const float* __restrict__ wk,
    const float* __restrict__ wv, u16* __restrict__ wP)
{
    int u    = blockIdx.x * 256 + threadIdx.x;   // 0..24575
    int ln   = u & 63;
    int frag = u >> 6;                           // 0..383
    int ksg  = frag & 31;
    int j16  = frag >> 5;                        // 0..11
    int n    = j16 * 16 + (ln & 15);
    int kb   = ksg * 32 + (ln >> 4) * 8;
    const float* src = (n < 64) ? (wq + (size_t)n * C_)
                     : (n < 128) ? (wk + (size_t)(n - 64) * C_)
                                 : (wv + (size_t)(n - 128) * C_);
    float4 f0 = *(const float4*)(src + kb);
    float4 f1 = *(const float4*)(src + kb + 4);
    *(bf16x8*)(wP + (size_t)u * 8) = cvt8r(f0, f1);
}

// ---------------- Kernel 1: QKV projection (R18 known-good) ---------------
__global__ __launch_bounds__(512) void qkv(
    const float* __restrict__ x, const u16* __restrict__ wP,
    u16* __restrict__ qP, u16* __restrict__ kP, u16* __restrict__ vP)
{
    __shared__ __align__(16) char smem[32768];

    const int tid = threadIdx.x;
    const int ln  = tid & 63;
    const int w   = tid >> 6;                    // 0..7
    const int m0  = blockIdx.x * 32;

    const int lr = ln & 15;
    const int g  = ln >> 4;
    const int ms = w >> 2;
    const int nh = w & 3;

    f32x4 acc[3] = {};

    const int xrow = w * 4 + (ln >> 4);
    const int xc   = (ln & 15) ^ (xrow & 7);

#define STAGE(BUF, KC)                                                     \
    gll16(x + (size_t)(m0 + xrow) * C_ + (KC) * 64 + xc * 4,               \
          smem + (BUF) * 8192 + w * 1024)

    STAGE(0, 0);
    __syncthreads();

    const int ra  = ms * 16 + lr;
    const int rsw = ra & 7;
    const u16* wbase = wP + (size_t)(nh * 3) * 32 * 64 * 8;

    for (int kc = 0; kc < 16; ++kc) {
        const int buf = kc & 1;
        if (kc < 15) STAGE(buf ^ 1, kc + 1);

        const char* rb = smem + buf * 8192;

        bf16x8 a[2];
        #pragma unroll
        for (int ks = 0; ks < 2; ++ks) {
            int c0 = ks * 8 + g * 2;
            float4 fa = *(const float4*)(rb + ra * 256 + ((c0       ^ rsw) << 4));
            float4 fb = *(const float4*)(rb + ra * 256 + (((c0 + 1) ^ rsw) << 4));
            a[ks] = cvt8r(fa, fb);
        }

        #pragma unroll
        for (int j = 0; j < 3; ++j) {
            #pragma unroll
            for (int ks = 0; ks < 2; ++ks) {
                size_t fragofs = ((size_t)(j * 32 + kc * 2 + ks) * 64 + ln) * 8;
                bf16x8 b = *(const bf16x8*)(wbase + fragofs);
                acc[j] = __builtin_amdgcn_mfma_f32_16x16x32_bf16(a[ks], b, acc[j], 0, 0, 0);
            }
        }

        __syncthreads();
    }
#undef STAGE

    // epilogue: acc -> LDS f32 tile [32][201] -> packed coalesced writes
    float* tile = (float*)smem;
    #pragma unroll
    for (int j = 0; j < 3; ++j)
        #pragma unroll
        for (int i = 0; i < 4; ++i)
            tile[(ms * 16 + g * 4 + i) * 201 + nh * 48 + j * 16 + lr] = acc[j][i];
    __syncthreads();

    for (int uu = tid; uu < 768; uu += 512) {
        const int ln2 = uu & 63;
        const int lr2 = ln2 & 15;
        const int g2  = ln2 >> 4;
        if (uu < 512) {
            const int isK = uu >> 8;
            const int rem = uu & 255;
            const int u   = rem >> 7;
            const int ks  = (rem >> 6) & 1;
            const float* src = tile + (u * 16 + lr2) * 201 + isK * 64 + ks * 32 + g2 * 8;
            float4 f0 = *(const float4*)src;
            float4 f1 = *(const float4*)(src + 4);
            bf16x8 val = cvt8r(f0, f1);
            u16* dst = (isK ? kP : qP)
                     + ((size_t)(((m0 >> 4) + u) * 2 + ks) * 64 + ln2) * 8;
            *(bf16x8*)dst = val;
        } else {
            const int rem = uu - 512;
            const int jf  = rem >> 6;
            union { u16 h[8]; bf16x8 v; } ua;
            #pragma unroll
            for (int e = 0; e < 8; ++e)
                ua.h[e] = f2bf(tile[(g2 * 8 + e) * 201 + 128 + jf * 16 + lr2]);
            u16* dst = vP + ((size_t)((m0 >> 5) * 4 + jf) * 64 + ln2) * 8;
            *(bf16x8*)dst = ua.v;
        }
    }
}

// ---------------- Kernel 2: attention, all 8 segments in-block ------------
// Block = one 16-row q-tile; 8 waves = 8 KV segments; partials in LDS (f32);
// one intra-block barrier; merge + direct f32 out. No global partials, no
// reduce kernel, no device-scope fences.
__global__ __launch_bounds__(512) void attn(
    const u16* __restrict__ qP, const u16* __restrict__ kP,
    const u16* __restrict__ vP, float* __restrict__ out)
{
    __shared__ u16   ps[8][16 * 72];       // 18432 B
    __shared__ float part[8][16][66];      // 33792 B
    __shared__ float mlp[8][16][2];        // 1024 B

    const int tid  = threadIdx.x;
    const int lane = tid & 63;
    const int seg  = tid >> 6;             // 0..7
    const int tix  = blockIdx.x;
    const int b    = tix & 3;
    const int qt   = 127 - (tix >> 2);
    const int q0   = qt * 16;

    const int lr = lane & 15;
    const int g  = lane >> 4;
    const int lk = g * 8;

    const int nch = (qt >> 2) + 1;
    const int L   = (nch + NSEG - 1) >> 3;
    const int c0  = seg * L;
    const int c1  = min(nch, c0 + L);

    if (c0 >= c1) {
        if (lr == 0)
            #pragma unroll
            for (int i = 0; i < 4; ++i) {
                mlp[seg][g * 4 + i][0] = -1e30f;
                mlp[seg][g * 4 + i][1] = 0.f;
            }
    } else {
        // Q fragments: packed contiguous
        bf16x8 aq[2];
        #pragma unroll
        for (int ks = 0; ks < 2; ++ks)
            aq[ks] = *(const bf16x8*)(qP + ((size_t)((b * 128 + qt) * 2 + ks) * 64 + lane) * 8);

        f32x4 oacc[4] = {};
        float mrow[4], lrow[4];
        #pragma unroll
        for (int i = 0; i < 4; ++i) { mrow[i] = -1e30f; lrow[i] = 0.f; }

        u16* myps = ps[seg];

        for (int jc = c0; jc < c1; ++jc) {
            const int kv0 = jc << 6;

            bf16x8 bk[8];
            #pragma unroll
            for (int jf = 0; jf < 4; ++jf)
                #pragma unroll
                for (int ks = 0; ks < 2; ++ks)
                    bk[jf * 2 + ks] = *(const bf16x8*)(kP +
                        ((size_t)((b * 128 + (kv0 >> 4) + jf) * 2 + ks) * 64 + lane) * 8);

            f32x4 sacc[4] = {};
            #pragma unroll
            for (int jf = 0; jf < 4; ++jf)
                #pragma unroll
                for (int ks = 0; ks < 2; ++ks)
                    sacc[jf] = __builtin_amdgcn_mfma_f32_16x16x32_bf16(aq[ks], bk[jf * 2 + ks], sacc[jf], 0, 0, 0);

            // V fragments (contiguous) issued BEFORE softmax
            bf16x8 bv[8];
            #pragma unroll
            for (int ks2 = 0; ks2 < 2; ++ks2)
                #pragma unroll
                for (int jf = 0; jf < 4; ++jf)
                    bv[jf * 2 + ks2] = *(const bf16x8*)(vP +
                        ((size_t)((b * 64 + (kv0 >> 5) + ks2) * 4 + jf) * 64 + lane) * 8);

            const bool full = (kv0 + 63 <= q0);
            #pragma unroll
            for (int jf = 0; jf < 4; ++jf) {
                int col = kv0 + jf * 16 + lr;
                #pragma unroll
                for (int i = 0; i < 4; ++i) {
                    int row = q0 + g * 4 + i;
                    float val = sacc[jf][i] * 0.03125f;
                    sacc[jf][i] = (full || col <= row) ? val : -1e30f;
                }
            }

            float pnew[4][4];
            #pragma unroll
            for (int i = 0; i < 4; ++i) {
                float mx = fmaxf(fmaxf(sacc[0][i], sacc[1][i]), fmaxf(sacc[2][i], sacc[3][i]));
                mx = fmaxf(mx, __shfl_xor(mx, 1));
                mx = fmaxf(mx, __shfl_xor(mx, 2));
                mx = fmaxf(mx, __shfl_xor(mx, 4));
                mx = fmaxf(mx, __shfl_xor(mx, 8));
                float mnew = fmaxf(mrow[i], mx);
                float corr = __expf(mrow[i] - mnew);
                float rs = 0.f;
                #pragma unroll
                for (int jf = 0; jf < 4; ++jf) {
                    float p = __expf(sacc[jf][i] - mnew);
                    pnew[jf][i] = p;
                    rs += p;
                }
                rs += __shfl_xor(rs, 1);
                rs += __shfl_xor(rs, 2);
                rs += __shfl_xor(rs, 4);
                rs += __shfl_xor(rs, 8);
                lrow[i] = lrow[i] * corr + rs;
                mrow[i] = mnew;
                #pragma unroll
                for (int jf = 0; jf < 4; ++jf) oacc[jf][i] *= corr;
            }

            // P -> LDS (wave-private slice; intra-wave ordering via lgkmcnt)
            #pragma unroll
            for (int jf = 0; jf < 4; ++jf)
                #pragma unroll
                for (int i = 0; i < 4; ++i)
                    myps[(g * 4 + i) * 72 + jf * 16 + lr] = f2bf(pnew[jf][i]);

            #pragma unroll
            for (int ks2 = 0; ks2 < 2; ++ks2) {
                bf16x8 ap = *(const bf16x8*)(myps + lr * 72 + ks2 * 32 + lk);
                #pragma unroll
                for (int jf = 0; jf < 4; ++jf)
                    oacc[jf] = __builtin_amdgcn_mfma_f32_16x16x32_bf16(ap, bv[jf * 2 + ks2], oacc[jf], 0, 0, 0);
            }
        }

        // f32 partials to LDS
        #pragma unroll
        for (int jf = 0; jf < 4; ++jf)
            #pragma unroll
            for (int i = 0; i < 4; ++i)
                part[seg][g * 4 + i][jf * 16 + lr] = oacc[jf][i];
        if (lr == 0)
            #pragma unroll
            for (int i = 0; i < 4; ++i) {
                mlp[seg][g * 4 + i][0] = mrow[i];
                mlp[seg][g * 4 + i][1] = lrow[i];
            }
    }

    __syncthreads();

    // -------- in-block merge (deterministic s=0..7 order), direct out -----
    if (tid < 256) {
        const int row = tid >> 4;
        const int p   = tid & 15;

        float m2[NSEG], l2[NSEG];
        #pragma unroll
        for (int s = 0; s < NSEG; ++s) {
            m2[s] = mlp[s][row][0];
            l2[s] = mlp[s][row][1];
        }
        float M = m2[0];
        #pragma unroll
        for (int s = 1; s < NSEG; ++s) M = fmaxf(M, m2[s]);

        float a0 = 0.f, a1 = 0.f, a2 = 0.f, a3 = 0.f, Lsum = 0.f;
        #pragma unroll
        for (int s = 0; s < NSEG; ++s) {
            if (l2[s] != 0.f) {
                float wgt = __expf(m2[s] - M);
                Lsum += l2[s] * wgt;
                const float* pp = &part[s][row][p * 4];
                a0 += wgt * pp[0];
                a1 += wgt * pp[1];
                a2 += wgt * pp[2];
                a3 += wgt * pp[3];
            }
        }
        float inv = 1.f / Lsum;
        float4 r; r.x = a0 * inv; r.y = a1 * inv; r.z = a2 * inv; r.w = a3 * inv;
        *(float4*)(out + ((size_t)b * T_ + qt * 16 + row) * H_ + p * 4) = r;
    }
}

extern "C" void kernel_launch(void* const* d_in, const int* in_sizes, int n_in,
                              void* d_out, int out_size, void* d_ws, size_t ws_size,
                              hipStream_t stream) {
    const float* x  = (const float*)d_in[0];
    const float* wq = (const float*)d_in[1];
    const float* wk = (const float*)d_in[2];
    const float* wv = (const float*)d_in[3];

    u16* qPws = (u16*)d_ws;                          // 1 MB
    u16* kPws = qPws + (size_t)B_ * T_ * H_;         // 1 MB
    u16* vPws = kPws + (size_t)B_ * T_ * H_;         // 1 MB
    u16* wPws = vPws + (size_t)B_ * T_ * H_;         // 384 KB

    wpack<<<96, 256, 0, stream>>>(wq, wk, wv, wPws);
    qkv<<<256, 512, 0, stream>>>(x, wPws, qPws, kPws, vPws);
    attn<<<512, 512, 0, stream>>>(qPws, kPws, vPws, (float*)d_out);
}

// Round 25
// 38.656 us; speedup vs baseline: 1.9679x; 1.0287x over previous
//
#include <hip/hip_runtime.h>
#include <hip/hip_bf16.h>

typedef unsigned short u16;
typedef __attribute__((ext_vector_type(8))) __bf16 bf16x8;
typedef __attribute__((ext_vector_type(4))) float f32x4;

#define B_ 4
#define T_ 2048
#define C_ 1024
#define H_ 64
#define NSEG 8

__device__ __forceinline__ u16 f2bf(float f) {
    union { __hip_bfloat16 h; u16 u; } cv;
    cv.h = __float2bfloat16(f);
    return cv.u;
}

__device__ __forceinline__ bf16x8 cvt8r(float4 f0, float4 f1) {
    union { u16 h[8]; bf16x8 v; } ua;
    ua.h[0] = f2bf(f0.x); ua.h[1] = f2bf(f0.y);
    ua.h[2] = f2bf(f0.z); ua.h[3] = f2bf(f0.w);
    ua.h[4] = f2bf(f1.x); ua.h[5] = f2bf(f1.y);
    ua.h[6] = f2bf(f1.z); ua.h[7] = f2bf(f1.w);
    return ua.v;
}

// async global -> LDS, 16B per lane; LDS dest = uniform base + lane*16
__device__ __forceinline__ void gll16(const void* g, void* l) {
    __builtin_amdgcn_global_load_lds(
        (const __attribute__((address_space(1))) void*)g,
        (__attribute__((address_space(3))) void*)l, 16, 0, 0);
}

// ---------------- Kernel 0: W fp32 -> FRAGMENT-PACKED bf16 ----------------
__global__ __launch_bounds__(256) void wpack(
    const float* __restrict__ wq, const float* __restrict__ wk,
    const float* __restrict__ wv, u16* __restrict__ wP)
{
    int u    = blockIdx.x * 256 + threadIdx.x;   // 0..24575
    int ln   = u & 63;
    int frag = u >> 6;                           // 0..383
    int ksg  = frag & 31;
    int j16  = frag >> 5;                        // 0..11
    int n    = j16 * 16 + (ln & 15);
    int kb   = ksg * 32 + (ln >> 4) * 8;
    const float* src = (n < 64) ? (wq + (size_t)n * C_)
                     : (n < 128) ? (wk + (size_t)(n - 64) * C_)
                                 : (wv + (size_t)(n - 128) * C_);
    float4 f0 = *(const float4*)(src + kb);
    float4 f1 = *(const float4*)(src + kb + 4);
    *(bf16x8*)(wP + (size_t)u * 8) = cvt8r(f0, f1);
}

// ---------------- Kernel 1: QKV projection, counted-vmcnt pipeline --------
// 256 blocks x 512 thr. 4-buffer x-staging, 3-deep prefetch; ONE raw
// s_barrier per chunk with counted vmcnt (prefetches stay in flight across
// barriers -> no vmcnt(0) drain). W B-frags direct from packed wP (L2).
__global__ __launch_bounds__(512) void qkv(
    const float* __restrict__ x, const u16* __restrict__ wP,
    u16* __restrict__ qP, u16* __restrict__ kP, u16* __restrict__ vP)
{
    __shared__ __align__(16) char smem[32768];   // 4 x 8KB staging | epilogue tile

    const int tid = threadIdx.x;
    const int ln  = tid & 63;
    const int w   = tid >> 6;                    // 0..7
    const int m0  = blockIdx.x * 32;

    const int lr = ln & 15;
    const int g  = ln >> 4;
    const int ms = w >> 2;
    const int nh = w & 3;

    f32x4 acc[3] = {};

    const int xrow = w * 4 + (ln >> 4);
    const int xc   = (ln & 15) ^ (xrow & 7);

#define STAGE(BUF, KC)                                                     \
    gll16(x + (size_t)(m0 + xrow) * C_ + (KC) * 64 + xc * 4,               \
          smem + (BUF) * 8192 + w * 1024)

    // prologue: 3-deep prefetch (1 gll16/wave each)
    STAGE(0, 0);
    STAGE(1, 1);
    STAGE(2, 2);

    const int ra  = ms * 16 + lr;
    const int rsw = ra & 7;
    const u16* wbase = wP + (size_t)(nh * 3) * 32 * 64 * 8;

    #pragma unroll
    for (int kc = 0; kc < 16; ++kc) {
        // wait ONLY for this chunk's stage (3 iterations old); newer stages
        // stay in flight. Outstanding stages: kc..min(15,kc+2).
        if (kc <= 13)      asm volatile("s_waitcnt vmcnt(2)" ::: "memory");
        else if (kc == 14) asm volatile("s_waitcnt vmcnt(1)" ::: "memory");
        else               asm volatile("s_waitcnt vmcnt(0)" ::: "memory");
        __builtin_amdgcn_s_barrier();            // all waves: buf staged, prev reads done
        __builtin_amdgcn_sched_barrier(0);       // pin ds_reads behind the wait

        const char* rb = smem + (kc & 3) * 8192;

        bf16x8 a[2];
        #pragma unroll
        for (int ks = 0; ks < 2; ++ks) {
            int c0 = ks * 8 + g * 2;
            float4 fa = *(const float4*)(rb + ra * 256 + ((c0       ^ rsw) << 4));
            float4 fb = *(const float4*)(rb + ra * 256 + (((c0 + 1) ^ rsw) << 4));
            a[ks] = cvt8r(fa, fb);
        }

        #pragma unroll
        for (int j = 0; j < 3; ++j) {
            #pragma unroll
            for (int ks = 0; ks < 2; ++ks) {
                size_t fragofs = ((size_t)(j * 32 + kc * 2 + ks) * 64 + ln) * 8;
                bf16x8 b = *(const bf16x8*)(wbase + fragofs);
                acc[j] = __builtin_amdgcn_mfma_f32_16x16x32_bf16(a[ks], b, acc[j], 0, 0, 0);
            }
        }

        // issue next prefetch at END of compute: its target buffer was last
        // read at kc-1, and all waves passed this chunk's barrier (=> done).
        if (kc < 13) STAGE((kc + 3) & 3, kc + 3);
    }
#undef STAGE

    __syncthreads();   // staging reads done before tile reuse (drains nothing: all stages consumed)

    // epilogue: acc -> LDS f32 tile [32][201] -> packed coalesced writes
    float* tile = (float*)smem;
    #pragma unroll
    for (int j = 0; j < 3; ++j)
        #pragma unroll
        for (int i = 0; i < 4; ++i)
            tile[(ms * 16 + g * 4 + i) * 201 + nh * 48 + j * 16 + lr] = acc[j][i];
    __syncthreads();

    for (int uu = tid; uu < 768; uu += 512) {
        const int ln2 = uu & 63;
        const int lr2 = ln2 & 15;
        const int g2  = ln2 >> 4;
        if (uu < 512) {
            const int isK = uu >> 8;
            const int rem = uu & 255;
            const int u   = rem >> 7;
            const int ks  = (rem >> 6) & 1;
            const float* src = tile + (u * 16 + lr2) * 201 + isK * 64 + ks * 32 + g2 * 8;
            float4 f0 = *(const float4*)src;
            float4 f1 = *(const float4*)(src + 4);
            bf16x8 val = cvt8r(f0, f1);
            u16* dst = (isK ? kP : qP)
                     + ((size_t)(((m0 >> 4) + u) * 2 + ks) * 64 + ln2) * 8;
            *(bf16x8*)dst = val;
        } else {
            const int rem = uu - 512;
            const int jf  = rem >> 6;
            union { u16 h[8]; bf16x8 v; } ua;
            #pragma unroll
            for (int e = 0; e < 8; ++e)
                ua.h[e] = f2bf(tile[(g2 * 8 + e) * 201 + 128 + jf * 16 + lr2]);
            u16* dst = vP + ((size_t)((m0 >> 5) * 4 + jf) * 64 + ln2) * 8;
            *(bf16x8*)dst = ua.v;
        }
    }
}

// ---------------- Kernel 2: attention, all 8 segments in-block ------------
__global__ __launch_bounds__(512) void attn(
    const u16* __restrict__ qP, const u16* __restrict__ kP,
    const u16* __restrict__ vP, float* __restrict__ out)
{
    __shared__ u16   ps[8][16 * 72];       // 18432 B
    __shared__ float part[8][16][66];      // 33792 B
    __shared__ float mlp[8][16][2];        // 1024 B

    const int tid  = threadIdx.x;
    const int lane = tid & 63;
    const int seg  = tid >> 6;             // 0..7
    const int tix  = blockIdx.x;
    const int b    = tix & 3;
    const int qt   = 127 - (tix >> 2);
    const int q0   = qt * 16;

    const int lr = lane & 15;
    const int g  = lane >> 4;
    const int lk = g * 8;

    const int nch = (qt >> 2) + 1;
    const int L   = (nch + NSEG - 1) >> 3;
    const int c0  = seg * L;
    const int c1  = min(nch, c0 + L);

    if (c0 >= c1) {
        if (lr == 0)
            #pragma unroll
            for (int i = 0; i < 4; ++i) {
                mlp[seg][g * 4 + i][0] = -1e30f;
                mlp[seg][g * 4 + i][1] = 0.f;
            }
    } else {
        bf16x8 aq[2];
        #pragma unroll
        for (int ks = 0; ks < 2; ++ks)
            aq[ks] = *(const bf16x8*)(qP + ((size_t)((b * 128 + qt) * 2 + ks) * 64 + lane) * 8);

        f32x4 oacc[4] = {};
        float mrow[4], lrow[4];
        #pragma unroll
        for (int i = 0; i < 4; ++i) { mrow[i] = -1e30f; lrow[i] = 0.f; }

        u16* myps = ps[seg];

        for (int jc = c0; jc < c1; ++jc) {
            const int kv0 = jc << 6;

            bf16x8 bk[8];
            #pragma unroll
            for (int jf = 0; jf < 4; ++jf)
                #pragma unroll
                for (int ks = 0; ks < 2; ++ks)
                    bk[jf * 2 + ks] = *(const bf16x8*)(kP +
                        ((size_t)((b * 128 + (kv0 >> 4) + jf) * 2 + ks) * 64 + lane) * 8);

            f32x4 sacc[4] = {};
            #pragma unroll
            for (int jf = 0; jf < 4; ++jf)
                #pragma unroll
                for (int ks = 0; ks < 2; ++ks)
                    sacc[jf] = __builtin_amdgcn_mfma_f32_16x16x32_bf16(aq[ks], bk[jf * 2 + ks], sacc[jf], 0, 0, 0);

            bf16x8 bv[8];
            #pragma unroll
            for (int ks2 = 0; ks2 < 2; ++ks2)
                #pragma unroll
                for (int jf = 0; jf < 4; ++jf)
                    bv[jf * 2 + ks2] = *(const bf16x8*)(vP +
                        ((size_t)((b * 64 + (kv0 >> 5) + ks2) * 4 + jf) * 64 + lane) * 8);

            const bool full = (kv0 + 63 <= q0);
            #pragma unroll
            for (int jf = 0; jf < 4; ++jf) {
                int col = kv0 + jf * 16 + lr;
                #pragma unroll
                for (int i = 0; i < 4; ++i) {
                    int row = q0 + g * 4 + i;
                    float val = sacc[jf][i] * 0.03125f;
                    sacc[jf][i] = (full || col <= row) ? val : -1e30f;
                }
            }

            float pnew[4][4];
            #pragma unroll
            for (int i = 0; i < 4; ++i) {
                float mx = fmaxf(fmaxf(sacc[0][i], sacc[1][i]), fmaxf(sacc[2][i], sacc[3][i]));
                mx = fmaxf(mx, __shfl_xor(mx, 1));
                mx = fmaxf(mx, __shfl_xor(mx, 2));
                mx = fmaxf(mx, __shfl_xor(mx, 4));
                mx = fmaxf(mx, __shfl_xor(mx, 8));
                float mnew = fmaxf(mrow[i], mx);
                float corr = __expf(mrow[i] - mnew);
                float rs = 0.f;
                #pragma unroll
                for (int jf = 0; jf < 4; ++jf) {
                    float p = __expf(sacc[jf][i] - mnew);
                    pnew[jf][i] = p;
                    rs += p;
                }
                rs += __shfl_xor(rs, 1);
                rs += __shfl_xor(rs, 2);
                rs += __shfl_xor(rs, 4);
                rs += __shfl_xor(rs, 8);
                lrow[i] = lrow[i] * corr + rs;
                mrow[i] = mnew;
                #pragma unroll
                for (int jf = 0; jf < 4; ++jf) oacc[jf][i] *= corr;
            }

            #pragma unroll
            for (int jf = 0; jf < 4; ++jf)
                #pragma unroll
                for (int i = 0; i < 4; ++i)
                    myps[(g * 4 + i) * 72 + jf * 16 + lr] = f2bf(pnew[jf][i]);

            #pragma unroll
            for (int ks2 = 0; ks2 < 2; ++ks2) {
                bf16x8 ap = *(const bf16x8*)(myps + lr * 72 + ks2 * 32 + lk);
                #pragma unroll
                for (int jf = 0; jf < 4; ++jf)
                    oacc[jf] = __builtin_amdgcn_mfma_f32_16x16x32_bf16(ap, bv[jf * 2 + ks2], oacc[jf], 0, 0, 0);
            }
        }

        #pragma unroll
        for (int jf = 0; jf < 4; ++jf)
            #pragma unroll
            for (int i = 0; i < 4; ++i)
                part[seg][g * 4 + i][jf * 16 + lr] = oacc[jf][i];
        if (lr == 0)
            #pragma unroll
            for (int i = 0; i < 4; ++i) {
                mlp[seg][g * 4 + i][0] = mrow[i];
                mlp[seg][g * 4 + i][1] = lrow[i];
            }
    }

    __syncthreads();

    if (tid < 256) {
        const int row = tid >> 4;
        const int p   = tid & 15;

        float m2[NSEG], l2[NSEG];
        #pragma unroll
        for (int s = 0; s < NSEG; ++s) {
            m2[s] = mlp[s][row][0];
            l2[s] = mlp[s][row][1];
        }
        float M = m2[0];
        #pragma unroll
        for (int s = 1; s < NSEG; ++s) M = fmaxf(M, m2[s]);

        float a0 = 0.f, a1 = 0.f, a2 = 0.f, a3 = 0.f, Lsum = 0.f;
        #pragma unroll
        for (int s = 0; s < NSEG; ++s) {
            if (l2[s] != 0.f) {
                float wgt = __expf(m2[s] - M);
                Lsum += l2[s] * wgt;
                const float* pp = &part[s][row][p * 4];
                a0 += wgt * pp[0];
                a1 += wgt * pp[1];
                a2 += wgt * pp[2];
                a3 += wgt * pp[3];
            }
        }
        float inv = 1.f / Lsum;
        float4 r; r.x = a0 * inv; r.y = a1 * inv; r.z = a2 * inv; r.w = a3 * inv;
        *(float4*)(out + ((size_t)b * T_ + qt * 16 + row) * H_ + p * 4) = r;
    }
}

extern "C" void kernel_launch(void* const* d_in, const int* in_sizes, int n_in,
                              void* d_out, int out_size, void* d_ws, size_t ws_size,
                              hipStream_t stream) {
    const float* x  = (const float*)d_in[0];
    const float* wq = (const float*)d_in[1];
    const float* wk = (const float*)d_in[2];
    const float* wv = (const float*)d_in[3];

    u16* qPws = (u16*)d_ws;                          // 1 MB
    u16* kPws = qPws + (size_t)B_ * T_ * H_;         // 1 MB
    u16* vPws = kPws + (size_t)B_ * T_ * H_;         // 1 MB
    u16* wPws = vPws + (size_t)B_ * T_ * H_;         // 384 KB

    wpack<<<96, 256, 0, stream>>>(wq, wk, wv, wPws);
    qkv<<<256, 512, 0, stream>>>(x, wPws, qPws, kPws, vPws);
    attn<<<512, 512, 0, stream>>>(qPws, kPws, vPws, (float*)d_out);
}

// Round 26
// 38.174 us; speedup vs baseline: 1.9927x; 1.0126x over previous
//
#include <hip/hip_runtime.h>
#include <hip/hip_bf16.h>

typedef unsigned short u16;
typedef __attribute__((ext_vector_type(8))) __bf16 bf16x8;
typedef __attribute__((ext_vector_type(4))) float f32x4;

#define B_ 4
#define T_ 2048
#define C_ 1024
#define H_ 64
#define NSEG 8

__device__ __forceinline__ u16 f2bf(float f) {
    union { __hip_bfloat16 h; u16 u; } cv;
    cv.h = __float2bfloat16(f);
    return cv.u;
}

__device__ __forceinline__ bf16x8 cvt8r(float4 f0, float4 f1) {
    union { u16 h[8]; bf16x8 v; } ua;
    ua.h[0] = f2bf(f0.x); ua.h[1] = f2bf(f0.y);
    ua.h[2] = f2bf(f0.z); ua.h[3] = f2bf(f0.w);
    ua.h[4] = f2bf(f1.x); ua.h[5] = f2bf(f1.y);
    ua.h[6] = f2bf(f1.z); ua.h[7] = f2bf(f1.w);
    return ua.v;
}

// async global -> LDS, 16B per lane; LDS dest = uniform base + lane*16
__device__ __forceinline__ void gll16(const void* g, void* l) {
    __builtin_amdgcn_global_load_lds(
        (const __attribute__((address_space(1))) void*)g,
        (__attribute__((address_space(3))) void*)l, 16, 0, 0);
}

// ---------------- Kernel 0: W fp32 -> FRAGMENT-PACKED bf16 ----------------
__global__ __launch_bounds__(256) void wpack(
    const float* __restrict__ wq, const float* __restrict__ wk,
    const float* __restrict__ wv, u16* __restrict__ wP)
{
    int u    = blockIdx.x * 256 + threadIdx.x;   // 0..24575
    int ln   = u & 63;
    int frag = u >> 6;                           // 0..383
    int ksg  = frag & 31;
    int j16  = frag >> 5;                        // 0..11
    int n    = j16 * 16 + (ln & 15);
    int kb   = ksg * 32 + (ln >> 4) * 8;
    const float* src = (n < 64) ? (wq + (size_t)n * C_)
                     : (n < 128) ? (wk + (size_t)(n - 64) * C_)
                                 : (wv + (size_t)(n - 128) * C_);
    float4 f0 = *(const float4*)(src + kb);
    float4 f1 = *(const float4*)(src + kb + 4);
    *(bf16x8*)(wP + (size_t)u * 8) = cvt8r(f0, f1);
}

// ---------------- Kernel 1: QKV projection, counted-vmcnt pipeline --------
__global__ __launch_bounds__(512) void qkv(
    const float* __restrict__ x, const u16* __restrict__ wP,
    u16* __restrict__ qP, u16* __restrict__ kP, u16* __restrict__ vP)
{
    __shared__ __align__(16) char smem[32768];   // 4 x 8KB staging | epilogue tile

    const int tid = threadIdx.x;
    const int ln  = tid & 63;
    const int w   = tid >> 6;                    // 0..7
    const int m0  = blockIdx.x * 32;

    const int lr = ln & 15;
    const int g  = ln >> 4;
    const int ms = w >> 2;
    const int nh = w & 3;

    f32x4 acc[3] = {};

    const int xrow = w * 4 + (ln >> 4);
    const int xc   = (ln & 15) ^ (xrow & 7);

#define STAGE(BUF, KC)                                                     \
    gll16(x + (size_t)(m0 + xrow) * C_ + (KC) * 64 + xc * 4,               \
          smem + (BUF) * 8192 + w * 1024)

    // prologue: 3-deep prefetch
    STAGE(0, 0);
    STAGE(1, 1);
    STAGE(2, 2);

    const int ra  = ms * 16 + lr;
    const int rsw = ra & 7;
    const u16* wbase = wP + (size_t)(nh * 3) * 32 * 64 * 8;

    #pragma unroll
    for (int kc = 0; kc < 16; ++kc) {
        if (kc <= 13)      asm volatile("s_waitcnt vmcnt(2)" ::: "memory");
        else if (kc == 14) asm volatile("s_waitcnt vmcnt(1)" ::: "memory");
        else               asm volatile("s_waitcnt vmcnt(0)" ::: "memory");
        __builtin_amdgcn_s_barrier();
        __builtin_amdgcn_sched_barrier(0);

        const char* rb = smem + (kc & 3) * 8192;

        bf16x8 a[2];
        #pragma unroll
        for (int ks = 0; ks < 2; ++ks) {
            int c0 = ks * 8 + g * 2;
            float4 fa = *(const float4*)(rb + ra * 256 + ((c0       ^ rsw) << 4));
            float4 fb = *(const float4*)(rb + ra * 256 + (((c0 + 1) ^ rsw) << 4));
            a[ks] = cvt8r(fa, fb);
        }

        #pragma unroll
        for (int j = 0; j < 3; ++j) {
            #pragma unroll
            for (int ks = 0; ks < 2; ++ks) {
                size_t fragofs = ((size_t)(j * 32 + kc * 2 + ks) * 64 + ln) * 8;
                bf16x8 b = *(const bf16x8*)(wbase + fragofs);
                acc[j] = __builtin_amdgcn_mfma_f32_16x16x32_bf16(a[ks], b, acc[j], 0, 0, 0);
            }
        }

        if (kc < 13) STAGE((kc + 3) & 3, kc + 3);
    }
#undef STAGE

    __syncthreads();

    // epilogue: acc -> LDS f32 tile [32][201] -> packed coalesced writes
    float* tile = (float*)smem;
    #pragma unroll
    for (int j = 0; j < 3; ++j)
        #pragma unroll
        for (int i = 0; i < 4; ++i)
            tile[(ms * 16 + g * 4 + i) * 201 + nh * 48 + j * 16 + lr] = acc[j][i];
    __syncthreads();

    for (int uu = tid; uu < 768; uu += 512) {
        const int ln2 = uu & 63;
        const int lr2 = ln2 & 15;
        const int g2  = ln2 >> 4;
        if (uu < 512) {
            const int isK = uu >> 8;
            const int rem = uu & 255;
            const int u   = rem >> 7;
            const int ks  = (rem >> 6) & 1;
            const float* src = tile + (u * 16 + lr2) * 201 + isK * 64 + ks * 32 + g2 * 8;
            float4 f0 = *(const float4*)src;
            float4 f1 = *(const float4*)(src + 4);
            bf16x8 val = cvt8r(f0, f1);
            u16* dst = (isK ? kP : qP)
                     + ((size_t)(((m0 >> 4) + u) * 2 + ks) * 64 + ln2) * 8;
            *(bf16x8*)dst = val;
        } else {
            const int rem = uu - 512;
            const int jf  = rem >> 6;
            union { u16 h[8]; bf16x8 v; } ua;
            #pragma unroll
            for (int e = 0; e < 8; ++e)
                ua.h[e] = f2bf(tile[(g2 * 8 + e) * 201 + 128 + jf * 16 + lr2]);
            u16* dst = vP + ((size_t)((m0 >> 5) * 4 + jf) * 64 + ln2) * 8;
            *(bf16x8*)dst = ua.v;
        }
    }
}

// ---------------- Kernel 2: attention, 8 segments in-block, LDS union ----
// ps (loop phase) and part/mlp (merge phase) alias one 34.8KB region ->
// 4 blocks/CU (was 2), 8 waves/SIMD of latency-hiding.
__global__ __launch_bounds__(512) void attn(
    const u16* __restrict__ qP, const u16* __restrict__ kP,
    const u16* __restrict__ vP, float* __restrict__ out)
{
    __shared__ __align__(16) char shm[34816];  // max(8*2304, 8*16*66*4 + 8*16*2*4)

    const int tid  = threadIdx.x;
    const int lane = tid & 63;
    const int seg  = tid >> 6;             // 0..7
    const int tix  = blockIdx.x;
    const int b    = tix & 3;
    const int qt   = 127 - (tix >> 2);
    const int q0   = qt * 16;

    const int lr = lane & 15;
    const int g  = lane >> 4;
    const int lk = g * 8;

    const int nch = (qt >> 2) + 1;
    const int L   = (nch + NSEG - 1) >> 3;
    const int c0  = seg * L;
    const int c1  = min(nch, c0 + L);

    f32x4 oacc[4] = {};
    float mrow[4], lrow[4];
    #pragma unroll
    for (int i = 0; i < 4; ++i) { mrow[i] = -1e30f; lrow[i] = 0.f; }

    if (c0 < c1) {
        bf16x8 aq[2];
        #pragma unroll
        for (int ks = 0; ks < 2; ++ks)
            aq[ks] = *(const bf16x8*)(qP + ((size_t)((b * 128 + qt) * 2 + ks) * 64 + lane) * 8);

        u16* myps = (u16*)shm + seg * 1152;    // 16*72 u16 per seg

        for (int jc = c0; jc < c1; ++jc) {
            const int kv0 = jc << 6;

            bf16x8 bk[8];
            #pragma unroll
            for (int jf = 0; jf < 4; ++jf)
                #pragma unroll
                for (int ks = 0; ks < 2; ++ks)
                    bk[jf * 2 + ks] = *(const bf16x8*)(kP +
                        ((size_t)((b * 128 + (kv0 >> 4) + jf) * 2 + ks) * 64 + lane) * 8);

            f32x4 sacc[4] = {};
            #pragma unroll
            for (int jf = 0; jf < 4; ++jf)
                #pragma unroll
                for (int ks = 0; ks < 2; ++ks)
                    sacc[jf] = __builtin_amdgcn_mfma_f32_16x16x32_bf16(aq[ks], bk[jf * 2 + ks], sacc[jf], 0, 0, 0);

            bf16x8 bv[8];
            #pragma unroll
            for (int ks2 = 0; ks2 < 2; ++ks2)
                #pragma unroll
                for (int jf = 0; jf < 4; ++jf)
                    bv[jf * 2 + ks2] = *(const bf16x8*)(vP +
                        ((size_t)((b * 64 + (kv0 >> 5) + ks2) * 4 + jf) * 64 + lane) * 8);

            const bool full = (kv0 + 63 <= q0);
            #pragma unroll
            for (int jf = 0; jf < 4; ++jf) {
                int col = kv0 + jf * 16 + lr;
                #pragma unroll
                for (int i = 0; i < 4; ++i) {
                    int row = q0 + g * 4 + i;
                    float val = sacc[jf][i] * 0.03125f;
                    sacc[jf][i] = (full || col <= row) ? val : -1e30f;
                }
            }

            float pnew[4][4];
            #pragma unroll
            for (int i = 0; i < 4; ++i) {
                float mx = fmaxf(fmaxf(sacc[0][i], sacc[1][i]), fmaxf(sacc[2][i], sacc[3][i]));
                mx = fmaxf(mx, __shfl_xor(mx, 1));
                mx = fmaxf(mx, __shfl_xor(mx, 2));
                mx = fmaxf(mx, __shfl_xor(mx, 4));
                mx = fmaxf(mx, __shfl_xor(mx, 8));
                float mnew = fmaxf(mrow[i], mx);
                float corr = __expf(mrow[i] - mnew);
                float rs = 0.f;
                #pragma unroll
                for (int jf = 0; jf < 4; ++jf) {
                    float p = __expf(sacc[jf][i] - mnew);
                    pnew[jf][i] = p;
                    rs += p;
                }
                rs += __shfl_xor(rs, 1);
                rs += __shfl_xor(rs, 2);
                rs += __shfl_xor(rs, 4);
                rs += __shfl_xor(rs, 8);
                lrow[i] = lrow[i] * corr + rs;
                mrow[i] = mnew;
                #pragma unroll
                for (int jf = 0; jf < 4; ++jf) oacc[jf][i] *= corr;
            }

            #pragma unroll
            for (int jf = 0; jf < 4; ++jf)
                #pragma unroll
                for (int i = 0; i < 4; ++i)
                    myps[(g * 4 + i) * 72 + jf * 16 + lr] = f2bf(pnew[jf][i]);

            #pragma unroll
            for (int ks2 = 0; ks2 < 2; ++ks2) {
                bf16x8 ap = *(const bf16x8*)(myps + lr * 72 + ks2 * 32 + lk);
                #pragma unroll
                for (int jf = 0; jf < 4; ++jf)
                    oacc[jf] = __builtin_amdgcn_mfma_f32_16x16x32_bf16(ap, bv[jf * 2 + ks2], oacc[jf], 0, 0, 0);
            }
        }
    }

    __syncthreads();   // ps region dead; safe to alias part/mlp onto it

    float* part = (float*)shm;                 // [8][16][66]
    float* mlp  = part + 8 * 16 * 66;          // [8][16][2]

    if (c0 >= c1) {
        if (lr == 0)
            #pragma unroll
            for (int i = 0; i < 4; ++i) {
                mlp[(seg * 16 + g * 4 + i) * 2]     = -1e30f;
                mlp[(seg * 16 + g * 4 + i) * 2 + 1] = 0.f;
            }
    } else {
        #pragma unroll
        for (int jf = 0; jf < 4; ++jf)
            #pragma unroll
            for (int i = 0; i < 4; ++i)
                part[(seg * 16 + g * 4 + i) * 66 + jf * 16 + lr] = oacc[jf][i];
        if (lr == 0)
            #pragma unroll
            for (int i = 0; i < 4; ++i) {
                mlp[(seg * 16 + g * 4 + i) * 2]     = mrow[i];
                mlp[(seg * 16 + g * 4 + i) * 2 + 1] = lrow[i];
            }
    }

    __syncthreads();

    if (tid < 256) {
        const int row = tid >> 4;
        const int p   = tid & 15;

        float m2[NSEG], l2[NSEG];
        #pragma unroll
        for (int s = 0; s < NSEG; ++s) {
            m2[s] = mlp[(s * 16 + row) * 2];
            l2[s] = mlp[(s * 16 + row) * 2 + 1];
        }
        float M = m2[0];
        #pragma unroll
        for (int s = 1; s < NSEG; ++s) M = fmaxf(M, m2[s]);

        float a0 = 0.f, a1 = 0.f, a2 = 0.f, a3 = 0.f, Lsum = 0.f;
        #pragma unroll
        for (int s = 0; s < NSEG; ++s) {
            if (l2[s] != 0.f) {
                float wgt = __expf(m2[s] - M);
                Lsum += l2[s] * wgt;
                const float* pp = part + (s * 16 + row) * 66 + p * 4;
                a0 += wgt * pp[0];
                a1 += wgt * pp[1];
                a2 += wgt * pp[2];
                a3 += wgt * pp[3];
            }
        }
        float inv = 1.f / Lsum;
        float4 r; r.x = a0 * inv; r.y = a1 * inv; r.z = a2 * inv; r.w = a3 * inv;
        *(float4*)(out + ((size_t)b * T_ + qt * 16 + row) * H_ + p * 4) = r;
    }
}

extern "C" void kernel_launch(void* const* d_in, const int* in_sizes, int n_in,
                              void* d_out, int out_size, void* d_ws, size_t ws_size,
                              hipStream_t stream) {
    const float* x  = (const float*)d_in[0];
    const float* wq = (const float*)d_in[1];
    const float* wk = (const float*)d_in[2];
    const float* wv = (const float*)d_in[3];

    u16* qPws = (u16*)d_ws;                          // 1 MB
    u16* kPws = qPws + (size_t)B_ * T_ * H_;         // 1 MB
    u16* vPws = kPws + (size_t)B_ * T_ * H_;         // 1 MB
    u16* wPws = vPws + (size_t)B_ * T_ * H_;         // 384 KB

    wpack<<<96, 256, 0, stream>>>(wq, wk, wv, wPws);
    qkv<<<256, 512, 0, stream>>>(x, wPws, qPws, kPws, vPws);
    attn<<<512, 512, 0, stream>>>(qPws, kPws, vPws, (float*)d_out);
}

// Round 27
// 37.912 us; speedup vs baseline: 2.0065x; 1.0069x over previous
//
#include <hip/hip_runtime.h>
#include <hip/hip_bf16.h>

typedef unsigned short u16;
typedef __attribute__((ext_vector_type(8))) __bf16 bf16x8;
typedef __attribute__((ext_vector_type(4))) float f32x4;

#define B_ 4
#define T_ 2048
#define C_ 1024
#define H_ 64
#define NSEG 8

__device__ __forceinline__ u16 f2bf(float f) {
    union { __hip_bfloat16 h; u16 u; } cv;
    cv.h = __float2bfloat16(f);
    return cv.u;
}

__device__ __forceinline__ bf16x8 cvt8r(float4 f0, float4 f1) {
    union { u16 h[8]; bf16x8 v; } ua;
    ua.h[0] = f2bf(f0.x); ua.h[1] = f2bf(f0.y);
    ua.h[2] = f2bf(f0.z); ua.h[3] = f2bf(f0.w);
    ua.h[4] = f2bf(f1.x); ua.h[5] = f2bf(f1.y);
    ua.h[6] = f2bf(f1.z); ua.h[7] = f2bf(f1.w);
    return ua.v;
}

// async global -> LDS, 16B per lane; LDS dest = uniform base + lane*16
__device__ __forceinline__ void gll16(const void* g, void* l) {
    __builtin_amdgcn_global_load_lds(
        (const __attribute__((address_space(1))) void*)g,
        (__attribute__((address_space(3))) void*)l, 16, 0, 0);
}

// ---------------- Kernel 0: W fp32 -> FRAGMENT-PACKED bf16 ----------------
__global__ __launch_bounds__(256) void wpack(
    const float* __restrict__ wq, const float* __restrict__ wk,
    const float* __restrict__ wv, u16* __restrict__ wP)
{
    int u    = blockIdx.x * 256 + threadIdx.x;   // 0..24575
    int ln   = u & 63;
    int frag = u >> 6;                           // 0..383
    int ksg  = frag & 31;
    int j16  = frag >> 5;                        // 0..11
    int n    = j16 * 16 + (ln & 15);
    int kb   = ksg * 32 + (ln >> 4) * 8;
    const float* src = (n < 64) ? (wq + (size_t)n * C_)
                     : (n < 128) ? (wk + (size_t)(n - 64) * C_)
                                 : (wv + (size_t)(n - 128) * C_);
    float4 f0 = *(const float4*)(src + kb);
    float4 f1 = *(const float4*)(src + kb + 4);
    *(bf16x8*)(wP + (size_t)u * 8) = cvt8r(f0, f1);
}

// ---------------- Kernel 1: QKV projection, counted-vmcnt pipeline --------
// 256 blocks x 512 thr. 4-buffer x-staging, 3-deep prefetch; ONE raw
// s_barrier per chunk with EXACT counted vmcnt. vmcnt retires in issue
// order, and the 6 B-loads/chunk share the counter: after stage(kc) the
// issue stream holds B(kc-2)x6 + stage(kc+1) + B(kc-1)x6 + stage(kc+2) = 14
// ops, so the steady-state wait is vmcnt(14) (NOT vmcnt(2) -- R25's bug).
__global__ __launch_bounds__(512) void qkv(
    const float* __restrict__ x, const u16* __restrict__ wP,
    u16* __restrict__ qP, u16* __restrict__ kP, u16* __restrict__ vP)
{
    __shared__ __align__(16) char smem[32768];   // 4 x 8KB staging | epilogue tile

    const int tid = threadIdx.x;
    const int ln  = tid & 63;
    const int w   = tid >> 6;                    // 0..7
    const int m0  = blockIdx.x * 32;

    const int lr = ln & 15;
    const int g  = ln >> 4;
    const int ms = w >> 2;
    const int nh = w & 3;

    f32x4 acc[3] = {};

    const int xrow = w * 4 + (ln >> 4);
    const int xc   = (ln & 15) ^ (xrow & 7);

#define STAGE(BUF, KC)                                                     \
    gll16(x + (size_t)(m0 + xrow) * C_ + (KC) * 64 + xc * 4,               \
          smem + (BUF) * 8192 + w * 1024)

    // prologue: 3-deep prefetch (1 gll16/wave each)
    STAGE(0, 0);
    STAGE(1, 1);
    STAGE(2, 2);

    const int ra  = ms * 16 + lr;
    const int rsw = ra & 7;
    const u16* wbase = wP + (size_t)(nh * 3) * 32 * 64 * 8;

    #pragma unroll
    for (int kc = 0; kc < 16; ++kc) {
        // exact post-stage(kc) issue counts (loop fully unrolled -> immediates)
        if (kc == 0)       asm volatile("s_waitcnt vmcnt(2)"  ::: "memory");
        else if (kc == 1)  asm volatile("s_waitcnt vmcnt(8)"  ::: "memory");
        else if (kc <= 13) asm volatile("s_waitcnt vmcnt(14)" ::: "memory");
        else if (kc == 14) asm volatile("s_waitcnt vmcnt(13)" ::: "memory");
        else               asm volatile("s_waitcnt vmcnt(12)" ::: "memory");
        __builtin_amdgcn_s_barrier();            // all waves: buf(kc) staged
        __builtin_amdgcn_sched_barrier(0);       // pin ds_reads behind the wait

        const char* rb = smem + (kc & 3) * 8192;

        bf16x8 a[2];
        #pragma unroll
        for (int ks = 0; ks < 2; ++ks) {
            int c0 = ks * 8 + g * 2;
            float4 fa = *(const float4*)(rb + ra * 256 + ((c0       ^ rsw) << 4));
            float4 fb = *(const float4*)(rb + ra * 256 + (((c0 + 1) ^ rsw) << 4));
            a[ks] = cvt8r(fa, fb);
        }

        #pragma unroll
        for (int j = 0; j < 3; ++j) {
            #pragma unroll
            for (int ks = 0; ks < 2; ++ks) {
                size_t fragofs = ((size_t)(j * 32 + kc * 2 + ks) * 64 + ln) * 8;
                bf16x8 b = *(const bf16x8*)(wbase + fragofs);
                acc[j] = __builtin_amdgcn_mfma_f32_16x16x32_bf16(a[ks], b, acc[j], 0, 0, 0);
            }
        }

        if (kc < 13) STAGE((kc + 3) & 3, kc + 3);
    }
#undef STAGE

    __syncthreads();

    // epilogue: acc -> LDS f32 tile [32][201] -> packed coalesced writes
    float* tile = (float*)smem;
    #pragma unroll
    for (int j = 0; j < 3; ++j)
        #pragma unroll
        for (int i = 0; i < 4; ++i)
            tile[(ms * 16 + g * 4 + i) * 201 + nh * 48 + j * 16 + lr] = acc[j][i];
    __syncthreads();

    for (int uu = tid; uu < 768; uu += 512) {
        const int ln2 = uu & 63;
        const int lr2 = ln2 & 15;
        const int g2  = ln2 >> 4;
        if (uu < 512) {
            const int isK = uu >> 8;
            const int rem = uu & 255;
            const int u   = rem >> 7;
            const int ks  = (rem >> 6) & 1;
            const float* src = tile + (u * 16 + lr2) * 201 + isK * 64 + ks * 32 + g2 * 8;
            float4 f0 = *(const float4*)src;
            float4 f1 = *(const float4*)(src + 4);
            bf16x8 val = cvt8r(f0, f1);
            u16* dst = (isK ? kP : qP)
                     + ((size_t)(((m0 >> 4) + u) * 2 + ks) * 64 + ln2) * 8;
            *(bf16x8*)dst = val;
        } else {
            const int rem = uu - 512;
            const int jf  = rem >> 6;
            union { u16 h[8]; bf16x8 v; } ua;
            #pragma unroll
            for (int e = 0; e < 8; ++e)
                ua.h[e] = f2bf(tile[(g2 * 8 + e) * 201 + 128 + jf * 16 + lr2]);
            u16* dst = vP + ((size_t)((m0 >> 5) * 4 + jf) * 64 + ln2) * 8;
            *(bf16x8*)dst = ua.v;
        }
    }
}

// ---------------- Kernel 2: attention, 8 segments in-block, LDS union ----
__global__ __launch_bounds__(512) void attn(
    const u16* __restrict__ qP, const u16* __restrict__ kP,
    const u16* __restrict__ vP, float* __restrict__ out)
{
    __shared__ __align__(16) char shm[34816];  // ps aliases part/mlp

    const int tid  = threadIdx.x;
    const int lane = tid & 63;
    const int seg  = tid >> 6;             // 0..7
    const int tix  = blockIdx.x;
    const int b    = tix & 3;
    const int qt   = 127 - (tix >> 2);
    const int q0   = qt * 16;

    const int lr = lane & 15;
    const int g  = lane >> 4;
    const int lk = g * 8;

    const int nch = (qt >> 2) + 1;
    const int L   = (nch + NSEG - 1) >> 3;
    const int c0  = seg * L;
    const int c1  = min(nch, c0 + L);

    f32x4 oacc[4] = {};
    float mrow[4], lrow[4];
    #pragma unroll
    for (int i = 0; i < 4; ++i) { mrow[i] = -1e30f; lrow[i] = 0.f; }

    if (c0 < c1) {
        bf16x8 aq[2];
        #pragma unroll
        for (int ks = 0; ks < 2; ++ks)
            aq[ks] = *(const bf16x8*)(qP + ((size_t)((b * 128 + qt) * 2 + ks) * 64 + lane) * 8);

        u16* myps = (u16*)shm + seg * 1152;

        for (int jc = c0; jc < c1; ++jc) {
            const int kv0 = jc << 6;

            bf16x8 bk[8];
            #pragma unroll
            for (int jf = 0; jf < 4; ++jf)
                #pragma unroll
                for (int ks = 0; ks < 2; ++ks)
                    bk[jf * 2 + ks] = *(const bf16x8*)(kP +
                        ((size_t)((b * 128 + (kv0 >> 4) + jf) * 2 + ks) * 64 + lane) * 8);

            f32x4 sacc[4] = {};
            #pragma unroll
            for (int jf = 0; jf < 4; ++jf)
                #pragma unroll
                for (int ks = 0; ks < 2; ++ks)
                    sacc[jf] = __builtin_amdgcn_mfma_f32_16x16x32_bf16(aq[ks], bk[jf * 2 + ks], sacc[jf], 0, 0, 0);

            bf16x8 bv[8];
            #pragma unroll
            for (int ks2 = 0; ks2 < 2; ++ks2)
                #pragma unroll
                for (int jf = 0; jf < 4; ++jf)
                    bv[jf * 2 + ks2] = *(const bf16x8*)(vP +
                        ((size_t)((b * 64 + (kv0 >> 5) + ks2) * 4 + jf) * 64 + lane) * 8);

            const bool full = (kv0 + 63 <= q0);
            #pragma unroll
            for (int jf = 0; jf < 4; ++jf) {
                int col = kv0 + jf * 16 + lr;
                #pragma unroll
                for (int i = 0; i < 4; ++i) {
                    int row = q0 + g * 4 + i;
                    float val = sacc[jf][i] * 0.03125f;
                    sacc[jf][i] = (full || col <= row) ? val : -1e30f;
                }
            }

            float pnew[4][4];
            #pragma unroll
            for (int i = 0; i < 4; ++i) {
                float mx = fmaxf(fmaxf(sacc[0][i], sacc[1][i]), fmaxf(sacc[2][i], sacc[3][i]));
                mx = fmaxf(mx, __shfl_xor(mx, 1));
                mx = fmaxf(mx, __shfl_xor(mx, 2));
                mx = fmaxf(mx, __shfl_xor(mx, 4));
                mx = fmaxf(mx, __shfl_xor(mx, 8));
                float mnew = fmaxf(mrow[i], mx);
                float corr = __expf(mrow[i] - mnew);
                float rs = 0.f;
                #pragma unroll
                for (int jf = 0; jf < 4; ++jf) {
                    float p = __expf(sacc[jf][i] - mnew);
                    pnew[jf][i] = p;
                    rs += p;
                }
                rs += __shfl_xor(rs, 1);
                rs += __shfl_xor(rs, 2);
                rs += __shfl_xor(rs, 4);
                rs += __shfl_xor(rs, 8);
                lrow[i] = lrow[i] * corr + rs;
                mrow[i] = mnew;
                #pragma unroll
                for (int jf = 0; jf < 4; ++jf) oacc[jf][i] *= corr;
            }

            #pragma unroll
            for (int jf = 0; jf < 4; ++jf)
                #pragma unroll
                for (int i = 0; i < 4; ++i)
                    myps[(g * 4 + i) * 72 + jf * 16 + lr] = f2bf(pnew[jf][i]);

            #pragma unroll
            for (int ks2 = 0; ks2 < 2; ++ks2) {
                bf16x8 ap = *(const bf16x8*)(myps + lr * 72 + ks2 * 32 + lk);
                #pragma unroll
                for (int jf = 0; jf < 4; ++jf)
                    oacc[jf] = __builtin_amdgcn_mfma_f32_16x16x32_bf16(ap, bv[jf * 2 + ks2], oacc[jf], 0, 0, 0);
            }
        }
    }

    __syncthreads();   // ps region dead; alias part/mlp onto it

    float* part = (float*)shm;                 // [8][16][66]
    float* mlp  = part + 8 * 16 * 66;          // [8][16][2]

    if (c0 >= c1) {
        if (lr == 0)
            #pragma unroll
            for (int i = 0; i < 4; ++i) {
                mlp[(seg * 16 + g * 4 + i) * 2]     = -1e30f;
                mlp[(seg * 16 + g * 4 + i) * 2 + 1] = 0.f;
            }
    } else {
        #pragma unroll
        for (int jf = 0; jf < 4; ++jf)
            #pragma unroll
            for (int i = 0; i < 4; ++i)
                part[(seg * 16 + g * 4 + i) * 66 + jf * 16 + lr] = oacc[jf][i];
        if (lr == 0)
            #pragma unroll
            for (int i = 0; i < 4; ++i) {
                mlp[(seg * 16 + g * 4 + i) * 2]     = mrow[i];
                mlp[(seg * 16 + g * 4 + i) * 2 + 1] = lrow[i];
            }
    }

    __syncthreads();

    if (tid < 256) {
        const int row = tid >> 4;
        const int p   = tid & 15;

        float m2[NSEG], l2[NSEG];
        #pragma unroll
        for (int s = 0; s < NSEG; ++s) {
            m2[s] = mlp[(s * 16 + row) * 2];
            l2[s] = mlp[(s * 16 + row) * 2 + 1];
        }
        float M = m2[0];
        #pragma unroll
        for (int s = 1; s < NSEG; ++s) M = fmaxf(M, m2[s]);

        float a0 = 0.f, a1 = 0.f, a2 = 0.f, a3 = 0.f, Lsum = 0.f;
        #pragma unroll
        for (int s = 0; s < NSEG; ++s) {
            if (l2[s] != 0.f) {
                float wgt = __expf(m2[s] - M);
                Lsum += l2[s] * wgt;
                const float* pp = part + (s * 16 + row) * 66 + p * 4;
                a0 += wgt * pp[0];
                a1 += wgt * pp[1];
                a2 += wgt * pp[2];
                a3 += wgt * pp[3];
            }
        }
        float inv = 1.f / Lsum;
        float4 r; r.x = a0 * inv; r.y = a1 * inv; r.z = a2 * inv; r.w = a3 * inv;
        *(float4*)(out + ((size_t)b * T_ + qt * 16 + row) * H_ + p * 4) = r;
    }
}

extern "C" void kernel_launch(void* const* d_in, const int* in_sizes, int n_in,
                              void* d_out, int out_size, void* d_ws, size_t ws_size,
                              hipStream_t stream) {
    const float* x  = (const float*)d_in[0];
    const float* wq = (const float*)d_in[1];
    const float* wk = (const float*)d_in[2];
    const float* wv = (const float*)d_in[3];

    u16* qPws = (u16*)d_ws;                          // 1 MB
    u16* kPws = qPws + (size_t)B_ * T_ * H_;         // 1 MB
    u16* vPws = kPws + (size_t)B_ * T_ * H_;         // 1 MB
    u16* wPws = vPws + (size_t)B_ * T_ * H_;         // 384 KB

    wpack<<<96, 256, 0, stream>>>(wq, wk, wv, wPws);
    qkv<<<256, 512, 0, stream>>>(x, wPws, qPws, kPws, vPws);
    attn<<<512, 512, 0, stream>>>(qPws, kPws, vPws, (float*)d_out);
}